// Round 10
// baseline (1476.322 us; speedup 1.0000x reference)
//
#include <hip/hip_runtime.h>
#include <hip/hip_bf16.h>

typedef __hip_bfloat16 bf16;
typedef unsigned short u16;
typedef unsigned int u32;
typedef unsigned char u8;
typedef __attribute__((ext_vector_type(8))) short bf16x8;
typedef __attribute__((ext_vector_type(4))) float f32x4;
typedef __attribute__((ext_vector_type(16))) float f32x16;

#define NB 8
#define CH 192
#define WSZ (CH*CH*9)
#define WBLK (CH*32)   // one [co][ci8] weight panel: 6144 u16 = 12 KB

// Activations channels-last: A[b][y][x][c], bf16. Convs write RAW outputs and
// accumulate masked per-batch BN stats into per-layer slots; consumers rebuild
// the affine in their prologue.
// Weights repacked to [slot][tap][ciblk32][co][ci8]: coalesced B-frag bursts.
// k_convm (Ho>=64) uses mfma_32x32x16: wave = 32 sites x 192 co -> per K16 step
// {1 ds_read_b128 + 6 B loads -> 6 MFMA32}. Block LDS traffic drops 4x vs the
// 16x16 shape (no cross-wave re-read of sites); B is wave-shared -> L1-served.

static __device__ __forceinline__ float bf2f(bf16 v){ return __bfloat162float(v); }
static __device__ __forceinline__ u16 f2bu(float f){
  union { bf16 h; u16 u; } cv; cv.h = __float2bfloat16(f); return cv.u;
}
static __device__ __forceinline__ float u2f(u16 u){
  union { bf16 h; u16 u; } cv; cv.u = u; return __bfloat162float(cv.h);
}
static __device__ __forceinline__ u32 pk2bf(float a, float b){
  union { __hip_bfloat162 h; u32 u; } cv;
  cv.h = __float22bfloat162_rn(make_float2(a, b));
  return cv.u;
}

// in-LDS per-channel affine rebuild from per-batch stats slot
static __device__ __forceinline__ void build_ss(const float* __restrict__ stIn,
        const float* __restrict__ g, const float* __restrict__ bb,
        const float* __restrict__ cnt, float* scs, float* shs, int t){
  if(t < CH){
    float s = 0.f, s2 = 0.f;
#pragma unroll
    for(int b=0;b<NB;b++){ s += stIn[b*384 + t]; s2 += stIn[b*384 + 192 + t]; }
    float n = fmaxf(*cnt, 1.0f);
    float mean = s/n;
    float var = fmaxf(s2/n - mean*mean, 0.f);
    float rstd = rsqrtf(var + 1e-5f);
    float sc = g[t]*rstd;
    scs[t] = sc;
    shs[t] = bb[t] - mean*sc;
  }
}

// 8-channel affine on a uint4 of bf16 (sc/sh 16B-aligned)
template<int RELU>
static __device__ __forceinline__ uint4 affine8(uint4 v, const float* scp, const float* shp){
  float4 sa = *(const float4*)(scp);
  float4 sb = *(const float4*)(scp+4);
  float4 ha = *(const float4*)(shp);
  float4 hb = *(const float4*)(shp+4);
  u16* pv = (u16*)&v;
  float f0, f1;
  f0 = u2f(pv[0])*sa.x + ha.x; f1 = u2f(pv[1])*sa.y + ha.y;
  if(RELU){ f0 = fmaxf(f0,0.f); f1 = fmaxf(f1,0.f); }
  ((u32*)&v)[0] = pk2bf(f0, f1);
  f0 = u2f(pv[2])*sa.z + ha.z; f1 = u2f(pv[3])*sa.w + ha.w;
  if(RELU){ f0 = fmaxf(f0,0.f); f1 = fmaxf(f1,0.f); }
  ((u32*)&v)[1] = pk2bf(f0, f1);
  f0 = u2f(pv[4])*sb.x + hb.x; f1 = u2f(pv[5])*sb.y + hb.y;
  if(RELU){ f0 = fmaxf(f0,0.f); f1 = fmaxf(f1,0.f); }
  ((u32*)&v)[2] = pk2bf(f0, f1);
  f0 = u2f(pv[6])*sb.z + hb.z; f1 = u2f(pv[7])*sb.w + hb.w;
  if(RELU){ f0 = fmaxf(f0,0.f); f1 = fmaxf(f1,0.f); }
  ((u32*)&v)[3] = pk2bf(f0, f1);
  return v;
}

// ---------------- utility kernels ----------------

__global__ void k_zero(float* p, int n){
  int i = blockIdx.x*blockDim.x + threadIdx.x;
  if(i < n) p[i] = 0.f;
}

__global__ void k_fill(float* p, int n, float v){
  int i = blockIdx.x*blockDim.x + threadIdx.x;
  if(i < n) p[i] = v;
}

__global__ void k_mask0(const int* __restrict__ mask, u8* __restrict__ m0){
  int i = blockIdx.x*blockDim.x + threadIdx.x;
  if(i >= NB*65536) return;
  int b = i >> 16; int p = i & 65535;
  int y = p >> 8, x = p & 255;
  int patch = (y >> 4)*16 + (x >> 4);
  m0[i] = (u8)(1 - mask[b*256 + patch]);
}

__global__ void k_maskdown(const u8* __restrict__ mi, u8* __restrict__ mo,
                           int Ho, int Wo, int Hi, int Wi){
  int i = blockIdx.x*blockDim.x + threadIdx.x;
  int total = NB*Ho*Wo; if(i >= total) return;
  int b = i/(Ho*Wo); int p = i%(Ho*Wo);
  int oy = p/Wo, ox = p%Wo;
  u8 v = 0;
  for(int ky=0; ky<3; ky++){
    int iy = oy*2 + ky - 1; if(iy < 0 || iy >= Hi) continue;
    for(int kx=0; kx<3; kx++){
      int ix = ox*2 + kx - 1; if(ix < 0 || ix >= Wi) continue;
      u8 t = mi[(b*Hi + iy)*Wi + ix]; if(t > v) v = t;
    }
  }
  mo[i] = v;
}

__global__ void k_count(const u8* __restrict__ m, int n, float* cnt){
  int i = blockIdx.x*blockDim.x + threadIdx.x;
  int stride = gridDim.x*blockDim.x;
  int local = 0;
  for(int j=i; j<n; j+=stride) local += m[j];
  for(int o=32; o>0; o>>=1) local += __shfl_down(local, o, 64);
  if((threadIdx.x & 63) == 0 && local) atomicAdd(cnt, (float)local);
}

// ---------------- stem BN stats via 9 masked image moments ----------------

__global__ __launch_bounds__(256) void k_moments(const float* __restrict__ im,
        const u8* __restrict__ m0, float* __restrict__ mom){
  float s[9];
#pragma unroll
  for(int k=0;k<9;k++) s[k]=0.f;
  int stride = gridDim.x*blockDim.x;
  for(int i = blockIdx.x*blockDim.x + threadIdx.x; i < NB*65536; i += stride){
    if(m0[i]){
      int b = i >> 16, p = i & 65535;
      float r = im[(size_t)(b*3+0)*65536 + p];
      float g = im[(size_t)(b*3+1)*65536 + p];
      float bl= im[(size_t)(b*3+2)*65536 + p];
      s[0]+=r;    s[1]+=g;    s[2]+=bl;
      s[3]+=r*r;  s[4]+=g*g;  s[5]+=bl*bl;
      s[6]+=r*g;  s[7]+=r*bl; s[8]+=g*bl;
    }
  }
#pragma unroll
  for(int k=0;k<9;k++){
    for(int o=32; o>0; o>>=1) s[k] += __shfl_down(s[k], o, 64);
  }
  __shared__ float sh[4][9];
  int w = threadIdx.x >> 6;
  if((threadIdx.x & 63) == 0){
#pragma unroll
    for(int k=0;k<9;k++) sh[w][k] = s[k];
  }
  __syncthreads();
  if(threadIdx.x < 9){
    float tt = sh[0][threadIdx.x] + sh[1][threadIdx.x] + sh[2][threadIdx.x] + sh[3][threadIdx.x];
    atomicAdd(&mom[threadIdx.x], tt);
  }
}

__global__ void k_stemfinal(const float* __restrict__ mom, const float* __restrict__ cnt,
        const float* __restrict__ sw, const float* __restrict__ g,
        const float* __restrict__ bb, float* __restrict__ ssA){
  int c = threadIdx.x; if(c >= CH) return;
  float n = fmaxf(*cnt, 1.0f);
  float m0=mom[0], m1=mom[1], m2=mom[2], m3=mom[3], m4=mom[4];
  float m5=mom[5], m6=mom[6], m7=mom[7], m8=mom[8];
  float w0 = sw[c*3+0], w1 = sw[c*3+1], w2 = sw[c*3+2];
  float mean = (w0*m0 + w1*m1 + w2*m2)/n;
  float e2 = (w0*w0*m3 + w1*w1*m4 + w2*w2*m5
            + 2.f*(w0*w1*m6 + w0*w2*m7 + w1*w2*m8))/n;
  float var = fmaxf(e2 - mean*mean, 0.f);
  float sc = g[c]*rsqrtf(var + 1e-5f);
  ssA[c] = sc;
  ssA[CH + c] = bb[c] - mean*sc;
}

__global__ void k_fold(const float* __restrict__ sw, const float* __restrict__ ssA,
                       float* __restrict__ swf){
  int c = threadIdx.x; if(c >= CH) return;
  float sc = ssA[c];
  swf[c*4+0] = sc*sw[c*3+0];
  swf[c*4+1] = sc*sw[c*3+1];
  swf[c*4+2] = sc*sw[c*3+2];
  swf[c*4+3] = ssA[CH+c];
}

// all 16 weight sets -> Wb16 slots [stage*4+sel][tap][ciblk32][co][ci8] bf16
__global__ void k_repack16(const float* __restrict__ dw1, const float* __restrict__ dw2,
                           const float* __restrict__ rw1, const float* __restrict__ rw2,
                           bf16* __restrict__ wb){
  int i = blockIdx.x*blockDim.x + threadIdx.x;
  if(i >= 16*WSZ) return;
  int stage = i/(4*WSZ);
  int sel = (i/WSZ)%4;
  int r = i%WSZ;
  const float* w = (sel==0)?dw1 : (sel==1)?dw2 : (sel==2)?rw1 : rw2;
  float val = w[(size_t)stage*WSZ + r];
  int tap = r%9; int ci = (r/9)%CH; int co = r/(9*CH);
  wb[(size_t)(stage*4+sel)*WSZ + ((size_t)(tap*6 + (ci>>5))*CH + co)*32 + (ci&31)]
      = __float2bfloat16(val);
}

// final 1x1 weights -> bf16 [ciblk32][co][ci8]
__global__ void k_repackF(const float* __restrict__ fw, bf16* __restrict__ wb){
  int i = blockIdx.x*blockDim.x + threadIdx.x;
  if(i >= CH*CH) return;
  int co = i/CH, ci = i%CH;
  wb[((size_t)(ci>>5)*CH + co)*32 + (ci&31)] = __float2bfloat16(fw[i]);
}

// ---------------- 4-mt epilogues (64-site blocks, 192 co) ----------------

static __device__ __forceinline__ void epi_stats(f32x4 (&acc)[4][3], const u8* sm,
        float* __restrict__ statsB, int b, int co0, int l15, int q, int lane){
  float s[3], s2[3];
#pragma unroll
  for(int nt=0;nt<3;nt++){ s[nt]=0.f; s2[nt]=0.f; }
#pragma unroll
  for(int mt=0;mt<4;mt++){
#pragma unroll
    for(int r=0;r<4;r++){
      int site = mt*16 + q*4 + r;
      float mv = (float)sm[site];
#pragma unroll
      for(int nt=0;nt<3;nt++){
        float v = acc[mt][nt][r]*mv;
        s[nt] += v; s2[nt] += v*v;
      }
    }
  }
#pragma unroll
  for(int nt=0;nt<3;nt++){
    s[nt]  += __shfl_down(s[nt], 32, 64);  s[nt]  += __shfl_down(s[nt], 16, 64);
    s2[nt] += __shfl_down(s2[nt], 32, 64); s2[nt] += __shfl_down(s2[nt], 16, 64);
  }
  if(lane < 16){
#pragma unroll
    for(int nt=0;nt<3;nt++){
      int co = co0 + nt*16 + l15;
      atomicAdd(&statsB[b*384 + co], s[nt]);
      atomicAdd(&statsB[b*384 + 192 + co], s2[nt]);
    }
  }
}

// full 64-site epilogue (obuf needs 64*212 u16 = 27136 B)
static __device__ __forceinline__ void epi_store(f32x4 (&acc)[4][3], u16* obuf,
        u16* __restrict__ out, int b, int oy0, int ox0, int Ho, int Wo,
        int t, int co0, int l15, int q){
  __syncthreads();
#pragma unroll
  for(int mt=0;mt<4;mt++){
#pragma unroll
    for(int nt=0;nt<3;nt++){
      int co = co0 + nt*16 + l15;
#pragma unroll
      for(int r=0;r<4;r++){
        int site = mt*16 + q*4 + r;
        obuf[site*212 + co] = f2bu(acc[mt][nt][r]);
      }
    }
  }
  __syncthreads();
  for(int e=t; e<3072; e+=256){
    int r = e/384; int off = (e%384)*4;
    int sx = off/CH, co = off%CH;
    ushort4 v = *(const ushort4*)&obuf[(r*8+sx)*212 + co];
    *(ushort4*)(out + ((size_t)(b*Ho+oy0+r)*Wo + ox0)*CH + off) = v;
  }
}

// ---------------- 32x32 epilogues (wave = 32-site quarter, 192 co) ----------------
// C/D mapping: col(co) = lane&31, row = (reg&3) + 8*(reg>>2) + 4*(lane>>5)

static __device__ __forceinline__ void epi_stats32(f32x16 (&acc)[6], const u8* sm,
        float* __restrict__ statsB, int b, int w, int l31, int hi, int lane){
  float s[6], s2[6];
#pragma unroll
  for(int nt=0;nt<6;nt++){ s[nt]=0.f; s2[nt]=0.f; }
#pragma unroll
  for(int g=0;g<16;g++){
    int site = w*32 + (g&3) + 8*(g>>2) + 4*hi;
    float mv = (float)sm[site];
#pragma unroll
    for(int nt=0;nt<6;nt++){
      float v = acc[nt][g]*mv;
      s[nt] += v; s2[nt] += v*v;
    }
  }
#pragma unroll
  for(int nt=0;nt<6;nt++){
    s[nt]  += __shfl_down(s[nt], 32, 64);
    s2[nt] += __shfl_down(s2[nt], 32, 64);
  }
  if(lane < 32){
#pragma unroll
    for(int nt=0;nt<6;nt++){
      int co = nt*32 + l31;
      atomicAdd(&statsB[b*384 + co], s[nt]);
      atomicAdd(&statsB[b*384 + 192 + co], s2[nt]);
    }
  }
}

// half epilogue: waves {2h,2h+1} dump their quarters (local sites 0..63), then
// all threads copy 64 sites (8 rows) to global. obuf needs 64*212 u16 = 27136 B.
static __device__ __forceinline__ void epi_store32_h(f32x16 (&acc)[6], u16* obuf,
        u16* __restrict__ out, int b, int oy0, int ox0, int Ho, int Wo,
        int t, int w, int l31, int hi, int half){
  __syncthreads();
  if((w >> 1) == half){
    int lq = w & 1;     // quarter within this half
#pragma unroll
    for(int g=0;g<16;g++){
      int lsite = lq*32 + (g&3) + 8*(g>>2) + 4*hi;   // 0..63
#pragma unroll
      for(int nt=0;nt<6;nt++)
        obuf[lsite*212 + nt*32 + l31] = f2bu(acc[nt][g]);
    }
  }
  __syncthreads();
  for(int e=t; e<3072; e+=256){
    int r = e/384; int off = (e%384)*4;
    int sx = off/CH, co = off%CH;
    ushort4 v = *(const ushort4*)&obuf[(r*8+sx)*212 + co];
    *(ushort4*)(out + ((size_t)(b*Ho+oy0+half*8+r)*Wo + ox0)*CH + off) = v;
  }
}

// ---------------- 2-mt epilogues (co-split: 64 sites x 96 co per block) ----------------

static __device__ __forceinline__ void epi_statsT(f32x4 (&acc)[2][3], const u8* sm,
        float* __restrict__ statsB, int b, int co0, int l15, int q, int lane, int mh){
  float s[3], s2[3];
#pragma unroll
  for(int nt=0;nt<3;nt++){ s[nt]=0.f; s2[nt]=0.f; }
#pragma unroll
  for(int mt=0;mt<2;mt++){
#pragma unroll
    for(int r=0;r<4;r++){
      int site = mh*32 + mt*16 + q*4 + r;
      float mv = (float)sm[site];
#pragma unroll
      for(int nt=0;nt<3;nt++){
        float v = acc[mt][nt][r]*mv;
        s[nt] += v; s2[nt] += v*v;
      }
    }
  }
#pragma unroll
  for(int nt=0;nt<3;nt++){
    s[nt]  += __shfl_down(s[nt], 32, 64);  s[nt]  += __shfl_down(s[nt], 16, 64);
    s2[nt] += __shfl_down(s2[nt], 32, 64); s2[nt] += __shfl_down(s2[nt], 16, 64);
  }
  if(lane < 16){
#pragma unroll
    for(int nt=0;nt<3;nt++){
      int co = co0 + nt*16 + l15;
      atomicAdd(&statsB[b*384 + co], s[nt]);
      atomicAdd(&statsB[b*384 + 192 + co], s2[nt]);
    }
  }
}

// obuf: 64 sites x 104 (96 co + pad); writes the block's 96-co slice
static __device__ __forceinline__ void epi_storeT(f32x4 (&acc)[2][3], u16* obuf,
        u16* __restrict__ out, int b, int oy0, int ox0, int Ho, int Wo,
        int t, int w, int coh, int l15, int q, int mh){
  __syncthreads();
#pragma unroll
  for(int mt=0;mt<2;mt++){
#pragma unroll
    for(int nt=0;nt<3;nt++){
      int col = (w&1)*48 + nt*16 + l15;
#pragma unroll
      for(int r=0;r<4;r++){
        int site = mh*32 + mt*16 + q*4 + r;
        obuf[site*104 + col] = f2bu(acc[mt][nt][r]);
      }
    }
  }
  __syncthreads();
  for(int e=t; e<1536; e+=256){
    int site = e/24; int grp = e%24;
    ushort4 v = *(const ushort4*)&obuf[site*104 + grp*4];
    *(ushort4*)(out + ((size_t)(b*Ho+oy0+(site>>3))*Wo + ox0+(site&7))*CH + coh*96 + grp*4) = v;
  }
}

// ---------------- s1 3x3 conv: 16x8 tile, 2x96-ci passes, mfma_32x32x16 ----------------
// Wave w owns sites [w*32, w*32+32) x all 192 co (6 nt32). Per K16 step:
// {1 ds_read_b128 (A) + 6 coalesced B loads -> 6 MFMA32}.
#define CIP 104
template<int RELU>
__global__ __launch_bounds__(256) void k_convm(const bf16* __restrict__ in,
        const bf16* __restrict__ wb, const u8* __restrict__ mk,
        bf16* __restrict__ out, int Ho, int Wo,
        const float* __restrict__ stIn, const float* __restrict__ gIn,
        const float* __restrict__ bIn, const float* __restrict__ cnt,
        float* __restrict__ statsB){
  __shared__ __align__(16) u16 tile[180*CIP];   // 37440 B; obuf (27136 B) aliased
  __shared__ __align__(16) float scs[CH], shs[CH];
  __shared__ u8 sm[128];
  __shared__ u8 wmk[180];
  __shared__ int anyact;
  const int t = threadIdx.x;
  const int b = blockIdx.z;
  const int ox0 = blockIdx.x*8, oy0 = blockIdx.y*16;
  const int gy0 = oy0 - 1, gx0 = ox0 - 1;

  if(t == 0) anyact = 0;
  __syncthreads();
  if(t < 128){
    int r = t >> 3, c = t & 7;
    u8 mv = mk[(b*Ho + oy0 + r)*Wo + ox0 + c];
    sm[t] = mv;
    if(mv) anyact = 1;
  }
  for(int e=t; e<180; e+=256){
    int y = e/10, x = e%10;
    int gy = gy0 + y, gx = gx0 + x;
    u8 mv = 0;
    if(gy >= 0 && gy < Ho && gx >= 0 && gx < Wo) mv = mk[(b*Ho+gy)*Wo+gx];
    wmk[e] = mv;
  }
  __syncthreads();
  if(!anyact) return;

  build_ss(stIn, gIn, bIn, cnt, scs, shs, t);
  __syncthreads();

  const u16* inp = (const u16*)in;
  const int w = t >> 6;
  const int l = t & 63;
  const int l31 = l & 31, hi = l >> 5;
  f32x16 acc32[6];
#pragma unroll
  for(int nt=0;nt<6;nt++)
#pragma unroll
    for(int g=0;g<16;g++) acc32[nt][g] = 0.f;

  const int s = w*32 + l31;            // this lane's site in the 128-tile
  const int sy = s >> 3, sx = s & 7;
  const u16* wt = (const u16*)wb;
  const int bbase = l31*32 + hi*8;     // per-lane B offset within a 32-ci panel

  for(int p=0; p<2; p++){
    if(p) __syncthreads();            // pass-0 conv reads of tile done
    const int cb = p*96;
    for(int u=t; u<2160; u+=256){
      int site = u/12; int grp = u%12;
      int y = site/10, x = site%10;
      int gy = gy0 + y, gx = gx0 + x;
      uint4 v = {0u,0u,0u,0u};
      if(wmk[site]){
        v = *(const uint4*)(inp + ((size_t)(b*Ho+gy)*Wo+gx)*CH + cb + grp*8);
        v = affine8<RELU>(v, &scs[cb + grp*8], &shs[cb + grp*8]);
      }
      *(uint4*)&tile[site*CIP + grp*8] = v;
    }
    __syncthreads();
    for(int tap=0; tap<9; tap++){
      const int ky = tap/3, kx = tap%3;
      const u16* tb = &tile[((sy+ky)*10 + sx+kx)*CIP + hi*8];
#pragma unroll
      for(int k16=0;k16<6;k16++){
        bf16x8 a = *(const bf16x8*)(tb + k16*16);
        const u16* wp = wt + (size_t)(tap*6 + p*3 + (k16>>1))*WBLK + (k16&1)*16 + bbase;
#pragma unroll
        for(int nt=0;nt<6;nt++){
          bf16x8 bv = *(const bf16x8*)(wp + nt*1024);
          acc32[nt] = __builtin_amdgcn_mfma_f32_32x32x16_bf16(a, bv, acc32[nt], 0, 0, 0);
        }
      }
    }
  }
  epi_stats32(acc32, sm, statsB, b, w, l31, hi, l);
  epi_store32_h(acc32, tile, (u16*)out, b, oy0, ox0, Ho, Wo, t, w, l31, hi, 0);
  epi_store32_h(acc32, tile, (u16*)out, b, oy0, ox0, Ho, Wo, t, w, l31, hi, 1);
}

// ---------------- s1 3x3 conv, co-split tail shape: 8x8 tile, 64 sites x 96 co ----------------
#define CIPT 200
template<int RELU>
__global__ __launch_bounds__(256) void k_convmT(const bf16* __restrict__ in,
        const bf16* __restrict__ wb, const u8* __restrict__ mk,
        bf16* __restrict__ out, int Ho, int Wo,
        const float* __restrict__ stIn, const float* __restrict__ gIn,
        const float* __restrict__ bIn, const float* __restrict__ cnt,
        float* __restrict__ statsB){
  __shared__ __align__(16) u16 tile[100*CIPT];   // 40 KB; obuf (64*104*2 = 13312 B) aliased
  __shared__ __align__(16) float scs[CH], shs[CH];
  __shared__ u8 sm[64];
  __shared__ u8 wmk[100];
  __shared__ int anyact;
  const int t = threadIdx.x;
  const int zb = blockIdx.z;
  const int b = zb & (NB-1);
  const int coh = zb >> 3;            // 0/1: which 96-co half
  const int ox0 = blockIdx.x*8, oy0 = blockIdx.y*8;
  const int gy0 = oy0 - 1, gx0 = ox0 - 1;

  if(t == 0) anyact = 0;
  __syncthreads();
  if(t < 64){
    int r = t >> 3, c = t & 7;
    u8 mv = mk[(b*Ho + oy0 + r)*Wo + ox0 + c];
    sm[t] = mv;
    if(mv) anyact = 1;
  } else if(t < 164){
    int e = t - 64;
    int y = e/10, x = e%10;
    int gy = gy0 + y, gx = gx0 + x;
    u8 mv = 0;
    if(gy >= 0 && gy < Ho && gx >= 0 && gx < Wo) mv = mk[(b*Ho+gy)*Wo+gx];
    wmk[e] = mv;
  }
  __syncthreads();
  if(!anyact) return;

  build_ss(stIn, gIn, bIn, cnt, scs, shs, t);
  __syncthreads();

  const u16* inp = (const u16*)in;
  for(int u=t; u<2400; u+=256){
    int y = u/240; int rem = u%240; int x = rem/24; int cu = rem%24;
    int gy = gy0 + y, gx = gx0 + x;
    uint4 v = {0u,0u,0u,0u};
    if(wmk[y*10+x]){
      v = *(const uint4*)(inp + ((size_t)(b*Ho+gy)*Wo+gx)*CH + cu*8);
      v = affine8<RELU>(v, &scs[cu*8], &shs[cu*8]);
    }
    *(uint4*)&tile[(y*10+x)*CIPT + cu*8] = v;
  }
  __syncthreads();

  const int w = t >> 6;
  const int l = t & 63;
  const int l15 = l & 15, q = l >> 4;
  const int mh = w >> 1;              // site half: 0 -> sites 0..31, 1 -> 32..63
  f32x4 acc[2][3];
#pragma unroll
  for(int mt=0;mt<2;mt++)
#pragma unroll
    for(int nt=0;nt<3;nt++) acc[mt][nt] = (f32x4){0.f,0.f,0.f,0.f};

  int sy[2], sx[2];
#pragma unroll
  for(int mt=0;mt<2;mt++){ int s = mh*32 + mt*16 + l15; sy[mt] = s>>3; sx[mt] = s&7; }
  const int co0 = coh*96 + (w&1)*48;
  const u16* wt = (const u16*)wb;
  int bco[3];
#pragma unroll
  for(int nt=0;nt<3;nt++) bco[nt] = (co0 + nt*16 + l15)*32 + q*8;

  for(int tap=0; tap<9; tap++){
    const int ky = tap/3, kx = tap%3;
    const u16* tb[2];
#pragma unroll
    for(int mt=0;mt<2;mt++)
      tb[mt] = &tile[((sy[mt]+ky)*10 + sx[mt]+kx)*CIPT + q*8];
#pragma unroll
    for(int c=0;c<6;c++){
      const u16* wp = wt + (size_t)(tap*6 + c)*WBLK;
      bf16x8 a[2], bbv[3];
#pragma unroll
      for(int mt=0;mt<2;mt++) a[mt] = *(const bf16x8*)(tb[mt] + c*32);
#pragma unroll
      for(int nt=0;nt<3;nt++) bbv[nt] = *(const bf16x8*)(wp + bco[nt]);
#pragma unroll
      for(int mt=0;mt<2;mt++)
#pragma unroll
        for(int nt=0;nt<3;nt++)
          acc[mt][nt] = __builtin_amdgcn_mfma_f32_16x16x32_bf16(a[mt], bbv[nt], acc[mt][nt], 0, 0, 0);
    }
  }
  epi_statsT(acc, sm, statsB, b, co0, l15, q, l, mh);
  epi_storeT(acc, tile, (u16*)out, b, oy0, ox0, Ho, Wo, t, w, coh, l15, q, mh);
}

// ---------------- s2 3x3 conv, co-split shape: direct-global A-frags ----------------

__global__ __launch_bounds__(256) void k_convs2T(const bf16* __restrict__ in,
        const bf16* __restrict__ wb, const u8* __restrict__ mk,
        bf16* __restrict__ out, int Ho, int Wo, float* __restrict__ statsB){
  __shared__ __align__(16) u16 obuf[64*104];
  __shared__ u8 sm[64];
  __shared__ int anyact;
  const int t = threadIdx.x;
  const int zb = blockIdx.z;
  const int b = zb & (NB-1);
  const int coh = zb >> 3;
  const int ox0 = blockIdx.x*8, oy0 = blockIdx.y*8;
  const int Hi = Ho*2, Wi = Wo*2;

  if(t == 0) anyact = 0;
  __syncthreads();
  if(t < 64){
    int r = t >> 3, c = t & 7;
    u8 mv = mk[(b*Ho + oy0 + r)*Wo + ox0 + c];
    sm[t] = mv;
    if(mv) anyact = 1;
  }
  __syncthreads();
  if(!anyact) return;

  const u16* inp = (const u16*)in;
  const int w = t >> 6;
  const int l = t & 63;
  const int l15 = l & 15, q = l >> 4;
  const int mh = w >> 1;
  f32x4 acc[2][3];
#pragma unroll
  for(int mt=0;mt<2;mt++)
#pragma unroll
    for(int nt=0;nt<3;nt++) acc[mt][nt] = (f32x4){0.f,0.f,0.f,0.f};

  int gyb[2], gxb[2];
#pragma unroll
  for(int mt=0;mt<2;mt++){
    int s = mh*32 + mt*16 + l15;
    gyb[mt] = (oy0 + (s>>3))*2 - 1;
    gxb[mt] = (ox0 + (s&7))*2 - 1;
  }
  const int co0 = coh*96 + (w&1)*48;
  const bf16x8 zro = {0,0,0,0,0,0,0,0};
  const u16* wt = (const u16*)wb;
  int bco[3];
#pragma unroll
  for(int nt=0;nt<3;nt++) bco[nt] = (co0 + nt*16 + l15)*32 + q*8;

  for(int tap=0; tap<9; tap++){
    const int ky = tap/3, kx = tap%3;
    const u16* ap[2]; bool av[2];
#pragma unroll
    for(int mt=0;mt<2;mt++){
      int gy = gyb[mt] + ky, gx = gxb[mt] + kx;
      av[mt] = (gy >= 0 && gy < Hi && gx >= 0 && gx < Wi);
      ap[mt] = inp + ((size_t)(b*Hi+gy)*Wi+gx)*CH + q*8;
    }
#pragma unroll
    for(int c=0;c<6;c++){
      const u16* wp = wt + (size_t)(tap*6 + c)*WBLK;
      bf16x8 a[2], bbv[3];
#pragma unroll
      for(int mt=0;mt<2;mt++) a[mt] = av[mt] ? *(const bf16x8*)(ap[mt] + c*32) : zro;
#pragma unroll
      for(int nt=0;nt<3;nt++) bbv[nt] = *(const bf16x8*)(wp + bco[nt]);
#pragma unroll
      for(int mt=0;mt<2;mt++)
#pragma unroll
        for(int nt=0;nt<3;nt++)
          acc[mt][nt] = __builtin_amdgcn_mfma_f32_16x16x32_bf16(a[mt], bbv[nt], acc[mt][nt], 0, 0, 0);
    }
  }
  epi_statsT(acc, sm, statsB, b, co0, l15, q, l, mh);
  epi_storeT(acc, obuf, (u16*)out, b, oy0, ox0, Ho, Wo, t, w, coh, l15, q, mh);
}

// ---------------- stage-0 (256->128 s2): 16x8 tile, fused MFMA stem, 6x32-ci passes ----------------
#define CIP0 36
#define NS0 561   // 33 rows x 17 cols input halo sites
__global__ __launch_bounds__(256) void k_conv0m(const float* __restrict__ im,
        const float* __restrict__ swf, const u8* __restrict__ m0,
        const bf16* __restrict__ wb, const u8* __restrict__ mk,
        bf16* __restrict__ out, float* __restrict__ statsB){
  __shared__ __align__(16) u16 tile[NS0*CIP0];   // 40392 B; obuf (13568 B) aliased
  __shared__ __align__(16) u16 bfr[576*8];       // 9216 B packed site B-frags
  __shared__ u8 sm[128];
  __shared__ int anyact;
  const int t = threadIdx.x;
  const int b = blockIdx.z;
  const int ox0 = blockIdx.x*8, oy0 = blockIdx.y*16;

  if(t == 0) anyact = 0;
  __syncthreads();
  if(t < 128){
    int r = t >> 3, c = t & 7;
    u8 mv = mk[(b*128 + oy0 + r)*128 + ox0 + c];
    sm[t] = mv;
    if(mv) anyact = 1;
  }
  __syncthreads();
  if(!anyact) return;

  const int gy0 = oy0*2 - 1, gx0 = ox0*2 - 1;
  // pack site frags once: {r,g,b,1, rl,gl,bl,0} at active in-bounds sites, else 0
  for(int e=t; e<576; e+=256){
    u32 w0=0u, w1=0u, w2=0u, w3=0u;
    if(e < NS0){
      int y = e/17, x = e%17;
      int gy = gy0 + y, gx = gx0 + x;
      if(gy >= 0 && gy < 256 && gx >= 0 && gx < 256){
        int pi = gy*256 + gx;
        if(m0[b*65536 + pi]){
          float rm = im[(size_t)(b*3+0)*65536 + pi];
          float gm = im[(size_t)(b*3+1)*65536 + pi];
          float bm = im[(size_t)(b*3+2)*65536 + pi];
          float rh = u2f(f2bu(rm)), gh = u2f(f2bu(gm)), bh = u2f(f2bu(bm));
          w0 = pk2bf(rm, gm);      w1 = pk2bf(bm, 1.0f);
          w2 = pk2bf(rm-rh, gm-gh); w3 = pk2bf(bm-bh, 0.f);
        }
      }
    }
    *(uint4*)&bfr[e*8] = make_uint4(w0, w1, w2, w3);
  }
  // bfr ready after the first in-loop barrier

  const int w = t >> 6;
  const int l = t & 63;
  const int l15 = l & 15, q = l >> 4;
  const bf16x8 zf = {0,0,0,0,0,0,0,0};

  f32x4 acc[8][3];
#pragma unroll
  for(int mt=0;mt<8;mt++)
#pragma unroll
    for(int nt=0;nt<3;nt++) acc[mt][nt] = (f32x4){0.f,0.f,0.f,0.f};

  int siy[8], six[8];
#pragma unroll
  for(int mt=0;mt<8;mt++){ int s = mt*16 + l15; siy[mt] = (s>>3)*2; six[mt] = (s&7)*2; }
  const int co0 = w*48;
  const u16* wt = (const u16*)wb;
  int bco[3];
#pragma unroll
  for(int nt=0;nt<3;nt++) bco[nt] = (co0 + nt*16 + l15)*32 + q*8;

  for(int h=0; h<6; h++){
    __syncthreads();   // prev pass's conv reads of tile done (and bfr ready at h=0)
    // weight A-frags for this 32-channel pass
    bf16x8 af[2];
#pragma unroll
    for(int mtl=0;mtl<2;mtl++){
      af[mtl] = zf;
      if(q == 0){
        const float4 wv = *(const float4*)&swf[(h*32 + mtl*16 + l15)*4];
        u32 wlo = pk2bf(wv.x, wv.y);
        ((u32*)&af[mtl])[0] = wlo;
        ((u32*)&af[mtl])[1] = pk2bf(wv.z, wv.w);
        ((u32*)&af[mtl])[2] = wlo;
        ((u32*)&af[mtl])[3] = pk2bf(wv.z, 0.f);
      }
    }
    // stem via MFMA over 36 site-tiles (9 per wave); lane writes 4 ch of one site
#pragma unroll
    for(int i=0;i<9;i++){
      int nt = w + i*4;               // wave-uniform, 0..35
      int site = nt*16 + l15;
      bf16x8 bs = zf;
      if(q == 0) bs = *(const bf16x8*)&bfr[(site < 576 ? site : 575)*8];
#pragma unroll
      for(int mtl=0;mtl<2;mtl++){
        f32x4 d = __builtin_amdgcn_mfma_f32_16x16x32_bf16(af[mtl], bs,
                        (f32x4){0.f,0.f,0.f,0.f}, 0, 0, 0);
        if(site < NS0){
          u32 lo = pk2bf(fmaxf(d[0],0.f), fmaxf(d[1],0.f));
          u32 hi = pk2bf(fmaxf(d[2],0.f), fmaxf(d[3],0.f));
          *(uint2*)&tile[site*CIP0 + mtl*16 + q*4] = make_uint2(lo, hi);
        }
      }
    }
    __syncthreads();
    // conv MFMA over this pass's 32 input channels: one K=32 step per tap
    for(int tap=0; tap<9; tap++){
      const int ky = tap/3, kx = tap%3;
      const u16* wp = wt + (size_t)(tap*6 + h)*WBLK;
      bf16x8 a[8], bbv[3];
#pragma unroll
      for(int mt=0;mt<8;mt++)
        a[mt] = *(const bf16x8*)&tile[((siy[mt]+ky)*17 + six[mt]+kx)*CIP0 + q*8];
#pragma unroll
      for(int nt=0;nt<3;nt++) bbv[nt] = *(const bf16x8*)(wp + bco[nt]);
#pragma unroll
      for(int mt=0;mt<8;mt++)
#pragma unroll
        for(int nt=0;nt<3;nt++)
          acc[mt][nt] = __builtin_amdgcn_mfma_f32_16x16x32_bf16(a[mt], bbv[nt], acc[mt][nt], 0, 0, 0);
    }
  }
  epi_stats8_impl:;
  // 8-mt stats (inline, matches old epi_stats8)
  {
    float s[3], s2[3];
#pragma unroll
    for(int nt=0;nt<3;nt++){ s[nt]=0.f; s2[nt]=0.f; }
#pragma unroll
    for(int mt=0;mt<8;mt++){
#pragma unroll
      for(int r=0;r<4;r++){
        int site = mt*16 + q*4 + r;
        float mv = (float)sm[site];
#pragma unroll
        for(int nt=0;nt<3;nt++){
          float v = acc[mt][nt][r]*mv;
          s[nt] += v; s2[nt] += v*v;
        }
      }
    }
#pragma unroll
    for(int nt=0;nt<3;nt++){
      s[nt]  += __shfl_down(s[nt], 32, 64);  s[nt]  += __shfl_down(s[nt], 16, 64);
      s2[nt] += __shfl_down(s2[nt], 32, 64); s2[nt] += __shfl_down(s2[nt], 16, 64);
    }
    if(l < 16){
#pragma unroll
      for(int nt=0;nt<3;nt++){
        int co = co0 + nt*16 + l15;
        atomicAdd(&statsB[b*384 + co], s[nt]);
        atomicAdd(&statsB[b*384 + 192 + co], s2[nt]);
      }
    }
  }
  // 4 quarter stores (obuf aliased on tile)
#pragma unroll
  for(int qd=0; qd<4; qd++){
    __syncthreads();
#pragma unroll
    for(int mi=0; mi<2; mi++){
      int mt = qd*2 + mi;
#pragma unroll
      for(int nt=0;nt<3;nt++){
        int co = co0 + nt*16 + l15;
#pragma unroll
        for(int r=0;r<4;r++){
          int site = mi*16 + q*4 + r;   // local 0..31
          tile[site*212 + co] = f2bu(acc[mt][nt][r]);
        }
      }
    }
    __syncthreads();
    for(int e=t; e<1536; e+=256){
      int r = e/384; int off = (e%384)*4;
      int sx = off/CH, co = off%CH;
      ushort4 v = *(const ushort4*)&tile[(r*8+sx)*212 + co];
      *(ushort4*)((u16*)out + ((size_t)(b*128+oy0+qd*4+r)*128 + ox0)*CH + off) = v;
    }
  }
}

// ---------------- residual combine: X = relu(affD(D)*m + affB(B)*m), 8 elems/thread ----------------

__global__ __launch_bounds__(256) void k_resid(const bf16* __restrict__ xD,
        const bf16* __restrict__ xB, const u8* __restrict__ m,
        const float* __restrict__ stD, const float* __restrict__ gD, const float* __restrict__ bD,
        const float* __restrict__ stB, const float* __restrict__ gB, const float* __restrict__ bB,
        const float* __restrict__ cnt, bf16* __restrict__ out, int sites){
  __shared__ __align__(16) float scD[CH], shD[CH], scB[CH], shB[CH];
  const int t = threadIdx.x;
  build_ss(stD, gD, bD, cnt, scD, shD, t);
  build_ss(stB, gB, bB, cnt, scB, shB, t);
  __syncthreads();
  int idx = blockIdx.x*256 + t;
  int total = sites*24;           // 24 groups of 8 channels per site
  if(idx >= total) return;
  int si = idx/24; int c0 = (idx%24)*8;
  float mv = (float)m[si];
  const u16* pd = (const u16*)xD + (size_t)si*CH + c0;
  const u16* pb = (const u16*)xB + (size_t)si*CH + c0;
  uint4 vd = *(const uint4*)pd;
  uint4 vb = *(const uint4*)pb;
  u16* dd = (u16*)&vd; u16* db = (u16*)&vb;
  uint4 vo;
#pragma unroll
  for(int j=0;j<4;j++){
    int c = c0 + j*2;
    float f0 = (u2f(dd[j*2  ])*scD[c  ] + shD[c  ])*mv + (u2f(db[j*2  ])*scB[c  ] + shB[c  ])*mv;
    float f1 = (u2f(dd[j*2+1])*scD[c+1] + shD[c+1])*mv + (u2f(db[j*2+1])*scB[c+1] + shB[c+1])*mv;
    ((u32*)&vo)[j] = pk2bf(fmaxf(f0, 0.f), fmaxf(f1, 0.f));
  }
  *(uint4*)((u16*)out + (size_t)si*CH + c0) = vo;
}

// ---------------- final 1x1 conv as MFMA with fused per-batch stats ----------------

__global__ __launch_bounds__(256) void k_finalm(const bf16* __restrict__ in,
        const bf16* __restrict__ wb, const u8* __restrict__ m4,
        bf16* __restrict__ out, float* __restrict__ statsB){
  __shared__ __align__(16) u16 obuf[64*212];
  __shared__ u8 sm[64];
  __shared__ int anyact;
  const int t = threadIdx.x;
  const int b = blockIdx.z;
  const int base = blockIdx.x*64;

  if(t == 0) anyact = 0;
  __syncthreads();
  if(t < 64){
    u8 mv = m4[b*256 + base + t];
    sm[t] = mv;
    if(mv) anyact = 1;
  }
  __syncthreads();
  if(!anyact) return;

  const int w = t >> 6;
  const int l = t & 63;
  const int l15 = l & 15, q = l >> 4;
  const int co0 = w*48;
  f32x4 acc[4][3];
#pragma unroll
  for(int mt=0;mt<4;mt++)
#pragma unroll
    for(int nt=0;nt<3;nt++) acc[mt][nt] = (f32x4){0.f,0.f,0.f,0.f};

  const u16* inp = (const u16*)in + (size_t)(b*256 + base)*CH + q*8;
  const u16* wt = (const u16*)wb;
  int bco[3];
#pragma unroll
  for(int nt=0;nt<3;nt++) bco[nt] = (co0 + nt*16 + l15)*32 + q*8;
#pragma unroll
  for(int c=0;c<6;c++){
    const u16* wp = wt + (size_t)c*WBLK;
    bf16x8 a[4], bbv[3];
#pragma unroll
    for(int mt=0;mt<4;mt++)
      a[mt] = *(const bf16x8*)(inp + (size_t)(mt*16 + l15)*CH + c*32);
#pragma unroll
    for(int nt=0;nt<3;nt++) bbv[nt] = *(const bf16x8*)(wp + bco[nt]);
#pragma unroll
    for(int mt=0;mt<4;mt++)
#pragma unroll
      for(int nt=0;nt<3;nt++)
        acc[mt][nt] = __builtin_amdgcn_mfma_f32_16x16x32_bf16(a[mt], bbv[nt], acc[mt][nt], 0, 0, 0);
  }
  epi_stats(acc, sm, statsB, b, co0, l15, q, l);
  // Ho=32, Wo=8 maps (b, oy0=blk*8, rows r, cols sx) -> site b*256 + base + r*8 + sx
  epi_store(acc, obuf, (u16*)out, b, blockIdx.x*8, 0, 32, 8, t, co0, l15, q);
}

__global__ __launch_bounds__(256) void k_bnapply_out(const bf16* __restrict__ x,
        const u8* __restrict__ m, const float* __restrict__ stF,
        const float* __restrict__ g, const float* __restrict__ bb,
        const float* __restrict__ cnt, float* __restrict__ out){
  __shared__ __align__(16) float scs[CH], shs[CH];
  const int t = threadIdx.x;
  build_ss(stF, g, bb, cnt, scs, shs, t);
  __syncthreads();
  int i = blockIdx.x*256 + t;
  if(i >= NB*CH*256) return;
  int p = i % 256; int c = (i/256) % CH; int b = i/(256*CH);
  int si = b*256 + p;
  float v = bf2f(x[(size_t)si*CH + c])*scs[c] + shs[c];
  v *= (float)m[si];
  v = fmaxf(v, 0.f);
  out[i] = v;
}

// ---------------- tail ----------------

__global__ void k_tail(const int* __restrict__ mask, float* __restrict__ out){
  int i = blockIdx.x*blockDim.x + threadIdx.x;
  if(i < 2048){
    out[393216 + i] = (float)mask[i];
  } else if(i < 4096){
    int j = i - 2048;
    out[395264 + j] = (float)(j & 255);
  }
}

// ---------------- host orchestration ----------------

extern "C" void kernel_launch(void* const* d_in, const int* in_sizes, int n_in,
                              void* d_out, int out_size, void* d_ws, size_t ws_size,
                              hipStream_t stream){
  const float* images = (const float*)d_in[0];
  const int*   maskI  = (const int*)d_in[1];
  const float* stem_w = (const float*)d_in[2];
  const float* stem_g = (const float*)d_in[3];
  const float* stem_b = (const float*)d_in[4];
  const float* dw1 = (const float*)d_in[5];
  const float* dg1 = (const float*)d_in[6];
  const float* db1 = (const float*)d_in[7];
  const float* dw2 = (const float*)d_in[8];
  const float* dg2 = (const float*)d_in[9];
  const float* db2 = (const float*)d_in[10];
  const float* rw1 = (const float*)d_in[11];
  const float* rg1 = (const float*)d_in[12];
  const float* rb1 = (const float*)d_in[13];
  const float* rw2 = (const float*)d_in[14];
  const float* rg2 = (const float*)d_in[15];
  const float* rb2 = (const float*)d_in[16];
  const float* final_w = (const float*)d_in[17];
  const float* final_g = (const float*)d_in[18];
  const float* final_b = (const float*)d_in[19];
  float* outF = (float*)d_out;

  char* wsp = (char*)d_ws;
  auto alloc = [&](size_t bytes)->char*{
    char* p = wsp; wsp += (bytes + 255) & ~(size_t)255; return p;
  };
  bf16* S0 = (bf16*)alloc((size_t)NB*CH*16384*2);
  bf16* S1 = (bf16*)alloc((size_t)NB*CH*16384*2);
  bf16* S2 = (bf16*)alloc((size_t)NB*CH*16384*2);
  int Hs[5] = {256,128,64,32,16};
  u8* M[5];
  for(int l=0;l<5;l++) M[l] = (u8*)alloc((size_t)NB*Hs[l]*Hs[l]);
  bf16*  Wb16 = (bf16*)alloc((size_t)17*WSZ*2);      // 16 conv slots + final 1x1 slot
  float* swf = (float*)alloc(CH*4*4);
  float* statsB16 = (float*)alloc((size_t)17*NB*384*4);   // 16 conv slots + final slot
  float* statsF = (float*)alloc(384*4);                   // 9 image moments live here
  float* ssA   = (float*)alloc(2*CH*4);
  float* cnts  = (float*)alloc(8*4);
  size_t need = (size_t)(wsp - (char*)d_ws);

  if(ws_size < need){
    k_fill<<<(393216+255)/256, 256, 0, stream>>>(outF, 393216, 777.0f);
    k_tail<<<16, 256, 0, stream>>>(maskI, outF);
    return;
  }

  // ---- zero stats (ws poisoned every call) + repack all weights once ----
  int nz = 17*NB*384 + 384;
  k_zero<<<(nz+255)/256, 256, 0, stream>>>(statsB16, nz);
  k_zero<<<1, 32, 0, stream>>>(cnts, 8);
  k_repack16<<<(16*WSZ+255)/256, 256, 0, stream>>>(dw1, dw2, rw1, rw2, Wb16);
  k_repackF<<<(CH*CH+255)/256, 256, 0, stream>>>(final_w, Wb16 + (size_t)16*WSZ);

  // ---- mask pyramid + counts ----
  k_mask0<<<(NB*65536+255)/256, 256, 0, stream>>>(maskI, M[0]);
  for(int l=1;l<5;l++){
    int total = NB*Hs[l]*Hs[l];
    k_maskdown<<<(total+255)/256, 256, 0, stream>>>(M[l-1], M[l], Hs[l], Hs[l], Hs[l-1], Hs[l-1]);
  }
  for(int l=0;l<5;l++){
    int n = NB*Hs[l]*Hs[l];
    int blocks = (n + 256*64 - 1)/(256*64); if(blocks < 1) blocks = 1; if(blocks > 256) blocks = 256;
    k_count<<<blocks, 256, 0, stream>>>(M[l], n, cnts + l);
  }

  // ---- stem BN params via image moments + fold ----
  k_moments<<<512, 256, 0, stream>>>(images, M[0], statsF);
  k_stemfinal<<<1, CH, 0, stream>>>(statsF, cnts + 0, stem_w, stem_g, stem_b, ssA);
  k_fold<<<1, CH, 0, stream>>>(stem_w, ssA, swf);

  // ---- 4 stages ----
  bf16* X = nullptr;
  for(int i=0;i<4;i++){
    int Ho = Hs[i+1];
    int sites = NB*Ho*Ho;
    const u8* mk = M[i+1];
    const float* cnt = cnts + i + 1;
    bf16* A = S0;
    bf16* B = (i % 2 == 0) ? S1 : S2;
    bf16* C2 = (i == 0) ? S2 : X;
    const bf16* W0 = Wb16 + (size_t)(i*4+0)*WSZ;
    const bf16* W1 = Wb16 + (size_t)(i*4+1)*WSZ;
    const bf16* W2 = Wb16 + (size_t)(i*4+2)*WSZ;
    const bf16* W3 = Wb16 + (size_t)(i*4+3)*WSZ;
    float* st0 = statsB16 + (size_t)(i*4+0)*NB*384;
    float* st1 = statsB16 + (size_t)(i*4+1)*NB*384;
    float* st2 = statsB16 + (size_t)(i*4+2)*NB*384;
    float* st3 = statsB16 + (size_t)(i*4+3)*NB*384;

    dim3 gT(Ho/8, Ho/8, NB*2);          // co-split tail shape
    if(i == 0){
      k_conv0m<<<dim3(16, 8, NB), 256, 0, stream>>>(images, swf, M[0], W0, M[1], A, st0);
    } else {
      k_convs2T<<<gT, 256, 0, stream>>>(X, W0, mk, A, Ho, Ho, st0);
    }
    if(Ho >= 64){
      dim3 g2(Ho/8, Ho/16, NB);         // 16x8 32x32-MFMA shape
      k_convm<1><<<g2, 256, 0, stream>>>(A, W1, mk, B, Ho, Ho,
          st0, dg1 + i*CH, db1 + i*CH, cnt, st1);
      k_convm<0><<<g2, 256, 0, stream>>>(B, W2, mk, A, Ho, Ho,
          st1, dg2 + i*CH, db2 + i*CH, cnt, st2);
      k_convm<1><<<g2, 256, 0, stream>>>(A, W3, mk, C2, Ho, Ho,
          st2, rg1 + i*CH, rb1 + i*CH, cnt, st3);
    } else {
      k_convmT<1><<<gT, 256, 0, stream>>>(A, W1, mk, B, Ho, Ho,
          st0, dg1 + i*CH, db1 + i*CH, cnt, st1);
      k_convmT<0><<<gT, 256, 0, stream>>>(B, W2, mk, A, Ho, Ho,
          st1, dg2 + i*CH, db2 + i*CH, cnt, st2);
      k_convmT<1><<<gT, 256, 0, stream>>>(A, W3, mk, C2, Ho, Ho,
          st2, rg1 + i*CH, rb1 + i*CH, cnt, st3);
    }
    k_resid<<<(sites*24 + 255)/256, 256, 0, stream>>>(C2, B, mk,
        st3, rg2 + i*CH, rb2 + i*CH,
        st1, dg2 + i*CH, db2 + i*CH, cnt, B, sites);
    X = B;
  }

  // ---- final 1x1 (MFMA, fused stats) + BN + ReLU -> d_out (f32 NCHW) ----
  float* stF = statsB16 + (size_t)16*NB*384;
  k_finalm<<<dim3(4, 1, NB), 256, 0, stream>>>(X, Wb16 + (size_t)16*WSZ, M[4], S0, stF);
  k_bnapply_out<<<(NB*CH*256 + 255)/256, 256, 0, stream>>>(S0, M[4], stF,
      final_g, final_b, cnts + 4, outF);

  // ---- tail ----
  k_tail<<<16, 256, 0, stream>>>(maskI, outF);
}

// Round 11
// 1074.015 us; speedup vs baseline: 1.3746x; 1.3746x over previous
//
#include <hip/hip_runtime.h>
#include <hip/hip_bf16.h>

typedef __hip_bfloat16 bf16;
typedef unsigned short u16;
typedef unsigned int u32;
typedef unsigned char u8;
typedef __attribute__((ext_vector_type(8))) short bf16x8;
typedef __attribute__((ext_vector_type(4))) float f32x4;

#define NB 8
#define CH 192
#define WSZ (CH*CH*9)
#define WBLK (CH*32)   // one [co][ci8] weight panel: 6144 u16 = 12 KB

// Activations channels-last: A[b][y][x][c], bf16. Convs write RAW outputs and
// accumulate masked per-batch BN stats into per-layer slots; consumers rebuild
// the affine in their prologue.
// Weights repacked to [slot][tap][ciblk32][co][ci8]: each wave's B-frag load is
// one contiguous coalesced 1-KB burst (validated: conv0m −15%, convm large win).
// NOTE (r7): T14 reg-prefetch of staging REGRESSED — compiler already covers it.
// NOTE (r10): mfma_32x32x16 convm REGRESSED (+400 µs) — all 4 waves duplicate
// the B-stream (4x VMEM issue) and the 32x32 B-frag hits 64-B lane stride
// (half-utilized lines, FETCH 2x). The 16x16 shape's per-wave-partitioned
// coalesced B-loads are load-bearing; keep them.

static __device__ __forceinline__ float bf2f(bf16 v){ return __bfloat162float(v); }
static __device__ __forceinline__ u16 f2bu(float f){
  union { bf16 h; u16 u; } cv; cv.h = __float2bfloat16(f); return cv.u;
}
static __device__ __forceinline__ float u2f(u16 u){
  union { bf16 h; u16 u; } cv; cv.u = u; return __bfloat162float(cv.h);
}
static __device__ __forceinline__ u32 pk2bf(float a, float b){
  union { __hip_bfloat162 h; u32 u; } cv;
  cv.h = __float22bfloat162_rn(make_float2(a, b));
  return cv.u;
}

// in-LDS per-channel affine rebuild from per-batch stats slot
static __device__ __forceinline__ void build_ss(const float* __restrict__ stIn,
        const float* __restrict__ g, const float* __restrict__ bb,
        const float* __restrict__ cnt, float* scs, float* shs, int t){
  if(t < CH){
    float s = 0.f, s2 = 0.f;
#pragma unroll
    for(int b=0;b<NB;b++){ s += stIn[b*384 + t]; s2 += stIn[b*384 + 192 + t]; }
    float n = fmaxf(*cnt, 1.0f);
    float mean = s/n;
    float var = fmaxf(s2/n - mean*mean, 0.f);
    float rstd = rsqrtf(var + 1e-5f);
    float sc = g[t]*rstd;
    scs[t] = sc;
    shs[t] = bb[t] - mean*sc;
  }
}

// 8-channel affine on a uint4 of bf16 (sc/sh 16B-aligned)
template<int RELU>
static __device__ __forceinline__ uint4 affine8(uint4 v, const float* scp, const float* shp){
  float4 sa = *(const float4*)(scp);
  float4 sb = *(const float4*)(scp+4);
  float4 ha = *(const float4*)(shp);
  float4 hb = *(const float4*)(shp+4);
  u16* pv = (u16*)&v;
  float f0, f1;
  f0 = u2f(pv[0])*sa.x + ha.x; f1 = u2f(pv[1])*sa.y + ha.y;
  if(RELU){ f0 = fmaxf(f0,0.f); f1 = fmaxf(f1,0.f); }
  ((u32*)&v)[0] = pk2bf(f0, f1);
  f0 = u2f(pv[2])*sa.z + ha.z; f1 = u2f(pv[3])*sa.w + ha.w;
  if(RELU){ f0 = fmaxf(f0,0.f); f1 = fmaxf(f1,0.f); }
  ((u32*)&v)[1] = pk2bf(f0, f1);
  f0 = u2f(pv[4])*sb.x + hb.x; f1 = u2f(pv[5])*sb.y + hb.y;
  if(RELU){ f0 = fmaxf(f0,0.f); f1 = fmaxf(f1,0.f); }
  ((u32*)&v)[2] = pk2bf(f0, f1);
  f0 = u2f(pv[6])*sb.z + hb.z; f1 = u2f(pv[7])*sb.w + hb.w;
  if(RELU){ f0 = fmaxf(f0,0.f); f1 = fmaxf(f1,0.f); }
  ((u32*)&v)[3] = pk2bf(f0, f1);
  return v;
}

// ---------------- utility kernels ----------------

__global__ void k_zero(float* p, int n){
  int i = blockIdx.x*blockDim.x + threadIdx.x;
  if(i < n) p[i] = 0.f;
}

__global__ void k_fill(float* p, int n, float v){
  int i = blockIdx.x*blockDim.x + threadIdx.x;
  if(i < n) p[i] = v;
}

__global__ void k_mask0(const int* __restrict__ mask, u8* __restrict__ m0){
  int i = blockIdx.x*blockDim.x + threadIdx.x;
  if(i >= NB*65536) return;
  int b = i >> 16; int p = i & 65535;
  int y = p >> 8, x = p & 255;
  int patch = (y >> 4)*16 + (x >> 4);
  m0[i] = (u8)(1 - mask[b*256 + patch]);
}

__global__ void k_maskdown(const u8* __restrict__ mi, u8* __restrict__ mo,
                           int Ho, int Wo, int Hi, int Wi){
  int i = blockIdx.x*blockDim.x + threadIdx.x;
  int total = NB*Ho*Wo; if(i >= total) return;
  int b = i/(Ho*Wo); int p = i%(Ho*Wo);
  int oy = p/Wo, ox = p%Wo;
  u8 v = 0;
  for(int ky=0; ky<3; ky++){
    int iy = oy*2 + ky - 1; if(iy < 0 || iy >= Hi) continue;
    for(int kx=0; kx<3; kx++){
      int ix = ox*2 + kx - 1; if(ix < 0 || ix >= Wi) continue;
      u8 t = mi[(b*Hi + iy)*Wi + ix]; if(t > v) v = t;
    }
  }
  mo[i] = v;
}

__global__ void k_count(const u8* __restrict__ m, int n, float* cnt){
  int i = blockIdx.x*blockDim.x + threadIdx.x;
  int stride = gridDim.x*blockDim.x;
  int local = 0;
  for(int j=i; j<n; j+=stride) local += m[j];
  for(int o=32; o>0; o>>=1) local += __shfl_down(local, o, 64);
  if((threadIdx.x & 63) == 0 && local) atomicAdd(cnt, (float)local);
}

// ---------------- stem BN stats via 9 masked image moments ----------------

__global__ __launch_bounds__(256) void k_moments(const float* __restrict__ im,
        const u8* __restrict__ m0, float* __restrict__ mom){
  float s[9];
#pragma unroll
  for(int k=0;k<9;k++) s[k]=0.f;
  int stride = gridDim.x*blockDim.x;
  for(int i = blockIdx.x*blockDim.x + threadIdx.x; i < NB*65536; i += stride){
    if(m0[i]){
      int b = i >> 16, p = i & 65535;
      float r = im[(size_t)(b*3+0)*65536 + p];
      float g = im[(size_t)(b*3+1)*65536 + p];
      float bl= im[(size_t)(b*3+2)*65536 + p];
      s[0]+=r;    s[1]+=g;    s[2]+=bl;
      s[3]+=r*r;  s[4]+=g*g;  s[5]+=bl*bl;
      s[6]+=r*g;  s[7]+=r*bl; s[8]+=g*bl;
    }
  }
#pragma unroll
  for(int k=0;k<9;k++){
    for(int o=32; o>0; o>>=1) s[k] += __shfl_down(s[k], o, 64);
  }
  __shared__ float sh[4][9];
  int w = threadIdx.x >> 6;
  if((threadIdx.x & 63) == 0){
#pragma unroll
    for(int k=0;k<9;k++) sh[w][k] = s[k];
  }
  __syncthreads();
  if(threadIdx.x < 9){
    float tt = sh[0][threadIdx.x] + sh[1][threadIdx.x] + sh[2][threadIdx.x] + sh[3][threadIdx.x];
    atomicAdd(&mom[threadIdx.x], tt);
  }
}

__global__ void k_stemfinal(const float* __restrict__ mom, const float* __restrict__ cnt,
        const float* __restrict__ sw, const float* __restrict__ g,
        const float* __restrict__ bb, float* __restrict__ ssA){
  int c = threadIdx.x; if(c >= CH) return;
  float n = fmaxf(*cnt, 1.0f);
  float m0=mom[0], m1=mom[1], m2=mom[2], m3=mom[3], m4=mom[4];
  float m5=mom[5], m6=mom[6], m7=mom[7], m8=mom[8];
  float w0 = sw[c*3+0], w1 = sw[c*3+1], w2 = sw[c*3+2];
  float mean = (w0*m0 + w1*m1 + w2*m2)/n;
  float e2 = (w0*w0*m3 + w1*w1*m4 + w2*w2*m5
            + 2.f*(w0*w1*m6 + w0*w2*m7 + w1*w2*m8))/n;
  float var = fmaxf(e2 - mean*mean, 0.f);
  float sc = g[c]*rsqrtf(var + 1e-5f);
  ssA[c] = sc;
  ssA[CH + c] = bb[c] - mean*sc;
}

__global__ void k_fold(const float* __restrict__ sw, const float* __restrict__ ssA,
                       float* __restrict__ swf){
  int c = threadIdx.x; if(c >= CH) return;
  float sc = ssA[c];
  swf[c*4+0] = sc*sw[c*3+0];
  swf[c*4+1] = sc*sw[c*3+1];
  swf[c*4+2] = sc*sw[c*3+2];
  swf[c*4+3] = ssA[CH+c];
}

// all 16 weight sets -> Wb16 slots [stage*4+sel][tap][ciblk32][co][ci8] bf16
// (coalesced layout: a wave B-frag (16 co x 32 ci) is one contiguous 1-KB block)
__global__ void k_repack16(const float* __restrict__ dw1, const float* __restrict__ dw2,
                           const float* __restrict__ rw1, const float* __restrict__ rw2,
                           bf16* __restrict__ wb){
  int i = blockIdx.x*blockDim.x + threadIdx.x;
  if(i >= 16*WSZ) return;
  int stage = i/(4*WSZ);
  int sel = (i/WSZ)%4;
  int r = i%WSZ;
  const float* w = (sel==0)?dw1 : (sel==1)?dw2 : (sel==2)?rw1 : rw2;
  float val = w[(size_t)stage*WSZ + r];
  int tap = r%9; int ci = (r/9)%CH; int co = r/(9*CH);
  wb[(size_t)(stage*4+sel)*WSZ + ((size_t)(tap*6 + (ci>>5))*CH + co)*32 + (ci&31)]
      = __float2bfloat16(val);
}

// final 1x1 weights -> bf16 [ciblk32][co][ci8]
__global__ void k_repackF(const float* __restrict__ fw, bf16* __restrict__ wb){
  int i = blockIdx.x*blockDim.x + threadIdx.x;
  if(i >= CH*CH) return;
  int co = i/CH, ci = i%CH;
  wb[((size_t)(ci>>5)*CH + co)*32 + (ci&31)] = __float2bfloat16(fw[i]);
}

// ---------------- 4-mt epilogues (64-site blocks, 192 co) ----------------

static __device__ __forceinline__ void epi_stats(f32x4 (&acc)[4][3], const u8* sm,
        float* __restrict__ statsB, int b, int co0, int l15, int q, int lane){
  float s[3], s2[3];
#pragma unroll
  for(int nt=0;nt<3;nt++){ s[nt]=0.f; s2[nt]=0.f; }
#pragma unroll
  for(int mt=0;mt<4;mt++){
#pragma unroll
    for(int r=0;r<4;r++){
      int site = mt*16 + q*4 + r;
      float mv = (float)sm[site];
#pragma unroll
      for(int nt=0;nt<3;nt++){
        float v = acc[mt][nt][r]*mv;
        s[nt] += v; s2[nt] += v*v;
      }
    }
  }
#pragma unroll
  for(int nt=0;nt<3;nt++){
    s[nt]  += __shfl_down(s[nt], 32, 64);  s[nt]  += __shfl_down(s[nt], 16, 64);
    s2[nt] += __shfl_down(s2[nt], 32, 64); s2[nt] += __shfl_down(s2[nt], 16, 64);
  }
  if(lane < 16){
#pragma unroll
    for(int nt=0;nt<3;nt++){
      int co = co0 + nt*16 + l15;
      atomicAdd(&statsB[b*384 + co], s[nt]);
      atomicAdd(&statsB[b*384 + 192 + co], s2[nt]);
    }
  }
}

// full 64-site epilogue (obuf needs 64*212 u16 = 27136 B)
static __device__ __forceinline__ void epi_store(f32x4 (&acc)[4][3], u16* obuf,
        u16* __restrict__ out, int b, int oy0, int ox0, int Ho, int Wo,
        int t, int co0, int l15, int q){
  __syncthreads();
#pragma unroll
  for(int mt=0;mt<4;mt++){
#pragma unroll
    for(int nt=0;nt<3;nt++){
      int co = co0 + nt*16 + l15;
#pragma unroll
      for(int r=0;r<4;r++){
        int site = mt*16 + q*4 + r;
        obuf[site*212 + co] = f2bu(acc[mt][nt][r]);
      }
    }
  }
  __syncthreads();
  for(int e=t; e<3072; e+=256){
    int r = e/384; int off = (e%384)*4;
    int sx = off/CH, co = off%CH;
    ushort4 v = *(const ushort4*)&obuf[(r*8+sx)*212 + co];
    *(ushort4*)(out + ((size_t)(b*Ho+oy0+r)*Wo + ox0)*CH + off) = v;
  }
}

// ---------------- 8-mt epilogues (128-site block tiles) ----------------

static __device__ __forceinline__ void epi_stats8(f32x4 (&acc)[8][3], const u8* sm,
        float* __restrict__ statsB, int b, int co0, int l15, int q, int lane){
  float s[3], s2[3];
#pragma unroll
  for(int nt=0;nt<3;nt++){ s[nt]=0.f; s2[nt]=0.f; }
#pragma unroll
  for(int mt=0;mt<8;mt++){
#pragma unroll
    for(int r=0;r<4;r++){
      int site = mt*16 + q*4 + r;
      float mv = (float)sm[site];
#pragma unroll
      for(int nt=0;nt<3;nt++){
        float v = acc[mt][nt][r]*mv;
        s[nt] += v; s2[nt] += v*v;
      }
    }
  }
#pragma unroll
  for(int nt=0;nt<3;nt++){
    s[nt]  += __shfl_down(s[nt], 32, 64);  s[nt]  += __shfl_down(s[nt], 16, 64);
    s2[nt] += __shfl_down(s2[nt], 32, 64); s2[nt] += __shfl_down(s2[nt], 16, 64);
  }
  if(lane < 16){
#pragma unroll
    for(int nt=0;nt<3;nt++){
      int co = co0 + nt*16 + l15;
      atomicAdd(&statsB[b*384 + co], s[nt]);
      atomicAdd(&statsB[b*384 + 192 + co], s2[nt]);
    }
  }
}

// quarter epilogue: 32 sites = acc rows qd*4..qd*4+3 (obuf needs 32*212 u16 = 13568 B)
static __device__ __forceinline__ void epi_store_q(f32x4 (&acc)[8][3], u16* obuf,
        u16* __restrict__ out, int b, int oy0, int ox0, int Ho, int Wo,
        int t, int co0, int l15, int q, int qd){
  __syncthreads();
#pragma unroll
  for(int mi=0; mi<2; mi++){
    int mt = qd*2 + mi;
#pragma unroll
    for(int nt=0;nt<3;nt++){
      int co = co0 + nt*16 + l15;
#pragma unroll
      for(int r=0;r<4;r++){
        int site = mi*16 + q*4 + r;   // local 0..31
        obuf[site*212 + co] = f2bu(acc[mt][nt][r]);
      }
    }
  }
  __syncthreads();
  for(int e=t; e<1536; e+=256){
    int r = e/384; int off = (e%384)*4;
    int sx = off/CH, co = off%CH;
    ushort4 v = *(const ushort4*)&obuf[(r*8+sx)*212 + co];
    *(ushort4*)(out + ((size_t)(b*Ho+oy0+qd*4+r)*Wo + ox0)*CH + off) = v;
  }
}

// ---------------- 2-mt epilogues (co-split: 64 sites x 96 co per block) ----------------

static __device__ __forceinline__ void epi_statsT(f32x4 (&acc)[2][3], const u8* sm,
        float* __restrict__ statsB, int b, int co0, int l15, int q, int lane, int mh){
  float s[3], s2[3];
#pragma unroll
  for(int nt=0;nt<3;nt++){ s[nt]=0.f; s2[nt]=0.f; }
#pragma unroll
  for(int mt=0;mt<2;mt++){
#pragma unroll
    for(int r=0;r<4;r++){
      int site = mh*32 + mt*16 + q*4 + r;
      float mv = (float)sm[site];
#pragma unroll
      for(int nt=0;nt<3;nt++){
        float v = acc[mt][nt][r]*mv;
        s[nt] += v; s2[nt] += v*v;
      }
    }
  }
#pragma unroll
  for(int nt=0;nt<3;nt++){
    s[nt]  += __shfl_down(s[nt], 32, 64);  s[nt]  += __shfl_down(s[nt], 16, 64);
    s2[nt] += __shfl_down(s2[nt], 32, 64); s2[nt] += __shfl_down(s2[nt], 16, 64);
  }
  if(lane < 16){
#pragma unroll
    for(int nt=0;nt<3;nt++){
      int co = co0 + nt*16 + l15;
      atomicAdd(&statsB[b*384 + co], s[nt]);
      atomicAdd(&statsB[b*384 + 192 + co], s2[nt]);
    }
  }
}

// obuf: 64 sites x 104 (96 co + pad); writes the block's 96-co slice
static __device__ __forceinline__ void epi_storeT(f32x4 (&acc)[2][3], u16* obuf,
        u16* __restrict__ out, int b, int oy0, int ox0, int Ho, int Wo,
        int t, int w, int coh, int l15, int q, int mh){
  __syncthreads();
#pragma unroll
  for(int mt=0;mt<2;mt++){
#pragma unroll
    for(int nt=0;nt<3;nt++){
      int col = (w&1)*48 + nt*16 + l15;
#pragma unroll
      for(int r=0;r<4;r++){
        int site = mh*32 + mt*16 + q*4 + r;
        obuf[site*104 + col] = f2bu(acc[mt][nt][r]);
      }
    }
  }
  __syncthreads();
  for(int e=t; e<1536; e+=256){
    int site = e/24; int grp = e%24;
    ushort4 v = *(const ushort4*)&obuf[site*104 + grp*4];
    *(ushort4*)(out + ((size_t)(b*Ho+oy0+(site>>3))*Wo + ox0+(site&7))*CH + coh*96 + grp*4) = v;
  }
}

// ---------------- s1 3x3 conv: 16x8 tile, 2x96-ci passes, 24-MFMA K-steps ----------------
#define CIP 104
template<int RELU>
__global__ __launch_bounds__(256) void k_convm(const bf16* __restrict__ in,
        const bf16* __restrict__ wb, const u8* __restrict__ mk,
        bf16* __restrict__ out, int Ho, int Wo,
        const float* __restrict__ stIn, const float* __restrict__ gIn,
        const float* __restrict__ bIn, const float* __restrict__ cnt,
        float* __restrict__ statsB){
  __shared__ __align__(16) u16 tile[180*CIP];   // 37440 B; obuf (13568 B) aliased
  __shared__ __align__(16) float scs[CH], shs[CH];
  __shared__ u8 sm[128];
  __shared__ u8 wmk[180];
  __shared__ int anyact;
  const int t = threadIdx.x;
  const int b = blockIdx.z;
  const int ox0 = blockIdx.x*8, oy0 = blockIdx.y*16;
  const int gy0 = oy0 - 1, gx0 = ox0 - 1;

  if(t == 0) anyact = 0;
  __syncthreads();
  if(t < 128){
    int r = t >> 3, c = t & 7;
    u8 mv = mk[(b*Ho + oy0 + r)*Wo + ox0 + c];
    sm[t] = mv;
    if(mv) anyact = 1;
  }
  for(int e=t; e<180; e+=256){
    int y = e/10, x = e%10;
    int gy = gy0 + y, gx = gx0 + x;
    u8 mv = 0;
    if(gy >= 0 && gy < Ho && gx >= 0 && gx < Wo) mv = mk[(b*Ho+gy)*Wo+gx];
    wmk[e] = mv;
  }
  __syncthreads();
  if(!anyact) return;

  build_ss(stIn, gIn, bIn, cnt, scs, shs, t);
  __syncthreads();

  const u16* inp = (const u16*)in;
  const int w = t >> 6;
  const int l = t & 63;
  const int l15 = l & 15, q = l >> 4;
  f32x4 acc[8][3];
#pragma unroll
  for(int mt=0;mt<8;mt++)
#pragma unroll
    for(int nt=0;nt<3;nt++) acc[mt][nt] = (f32x4){0.f,0.f,0.f,0.f};

  int sy[8], sx[8];
#pragma unroll
  for(int mt=0;mt<8;mt++){ int s = mt*16 + l15; sy[mt] = s>>3; sx[mt] = s&7; }
  const int co0 = w*48;
  const u16* wt = (const u16*)wb;
  int bco[3];
#pragma unroll
  for(int nt=0;nt<3;nt++) bco[nt] = (co0 + nt*16 + l15)*32 + q*8;

  for(int p=0; p<2; p++){
    if(p) __syncthreads();            // pass-0 conv reads of tile done
    const int cb = p*96;
    for(int u=t; u<2160; u+=256){
      int site = u/12; int grp = u%12;
      int y = site/10, x = site%10;
      int gy = gy0 + y, gx = gx0 + x;
      uint4 v = {0u,0u,0u,0u};
      if(wmk[site]){
        v = *(const uint4*)(inp + ((size_t)(b*Ho+gy)*Wo+gx)*CH + cb + grp*8);
        v = affine8<RELU>(v, &scs[cb + grp*8], &shs[cb + grp*8]);
      }
      *(uint4*)&tile[site*CIP + grp*8] = v;
    }
    __syncthreads();
    for(int tap=0; tap<9; tap++){
      const int ky = tap/3, kx = tap%3;
      const u16* tb[8];
#pragma unroll
      for(int mt=0;mt<8;mt++)
        tb[mt] = &tile[((sy[mt]+ky)*10 + sx[mt]+kx)*CIP + q*8];
#pragma unroll
      for(int c=0;c<3;c++){
        const u16* wp = wt + (size_t)(tap*6 + p*3 + c)*WBLK;
        bf16x8 a[8], bbv[3];
#pragma unroll
        for(int mt=0;mt<8;mt++) a[mt] = *(const bf16x8*)(tb[mt] + c*32);
#pragma unroll
        for(int nt=0;nt<3;nt++) bbv[nt] = *(const bf16x8*)(wp + bco[nt]);
#pragma unroll
        for(int mt=0;mt<8;mt++)
#pragma unroll
          for(int nt=0;nt<3;nt++)
            acc[mt][nt] = __builtin_amdgcn_mfma_f32_16x16x32_bf16(a[mt], bbv[nt], acc[mt][nt], 0, 0, 0);
      }
    }
  }
  epi_stats8(acc, sm, statsB, b, co0, l15, q, l);
  epi_store_q(acc, tile, (u16*)out, b, oy0, ox0, Ho, Wo, t, co0, l15, q, 0);
  epi_store_q(acc, tile, (u16*)out, b, oy0, ox0, Ho, Wo, t, co0, l15, q, 1);
  epi_store_q(acc, tile, (u16*)out, b, oy0, ox0, Ho, Wo, t, co0, l15, q, 2);
  epi_store_q(acc, tile, (u16*)out, b, oy0, ox0, Ho, Wo, t, co0, l15, q, 3);
}

// ---------------- s1 3x3 conv, co-split tail shape: 8x8 tile, 64 sites x 96 co ----------------
#define CIPT 200
template<int RELU>
__global__ __launch_bounds__(256) void k_convmT(const bf16* __restrict__ in,
        const bf16* __restrict__ wb, const u8* __restrict__ mk,
        bf16* __restrict__ out, int Ho, int Wo,
        const float* __restrict__ stIn, const float* __restrict__ gIn,
        const float* __restrict__ bIn, const float* __restrict__ cnt,
        float* __restrict__ statsB){
  __shared__ __align__(16) u16 tile[100*CIPT];   // 40 KB; obuf (64*104*2 = 13312 B) aliased
  __shared__ __align__(16) float scs[CH], shs[CH];
  __shared__ u8 sm[64];
  __shared__ u8 wmk[100];
  __shared__ int anyact;
  const int t = threadIdx.x;
  const int zb = blockIdx.z;
  const int b = zb & (NB-1);
  const int coh = zb >> 3;            // 0/1: which 96-co half
  const int ox0 = blockIdx.x*8, oy0 = blockIdx.y*8;
  const int gy0 = oy0 - 1, gx0 = ox0 - 1;

  if(t == 0) anyact = 0;
  __syncthreads();
  if(t < 64){
    int r = t >> 3, c = t & 7;
    u8 mv = mk[(b*Ho + oy0 + r)*Wo + ox0 + c];
    sm[t] = mv;
    if(mv) anyact = 1;
  } else if(t < 164){
    int e = t - 64;
    int y = e/10, x = e%10;
    int gy = gy0 + y, gx = gx0 + x;
    u8 mv = 0;
    if(gy >= 0 && gy < Ho && gx >= 0 && gx < Wo) mv = mk[(b*Ho+gy)*Wo+gx];
    wmk[e] = mv;
  }
  __syncthreads();
  if(!anyact) return;

  build_ss(stIn, gIn, bIn, cnt, scs, shs, t);
  __syncthreads();

  const u16* inp = (const u16*)in;
  for(int u=t; u<2400; u+=256){
    int y = u/240; int rem = u%240; int x = rem/24; int cu = rem%24;
    int gy = gy0 + y, gx = gx0 + x;
    uint4 v = {0u,0u,0u,0u};
    if(wmk[y*10+x]){
      v = *(const uint4*)(inp + ((size_t)(b*Ho+gy)*Wo+gx)*CH + cu*8);
      v = affine8<RELU>(v, &scs[cu*8], &shs[cu*8]);
    }
    *(uint4*)&tile[(y*10+x)*CIPT + cu*8] = v;
  }
  __syncthreads();

  const int w = t >> 6;
  const int l = t & 63;
  const int l15 = l & 15, q = l >> 4;
  const int mh = w >> 1;              // site half: 0 -> sites 0..31, 1 -> 32..63
  f32x4 acc[2][3];
#pragma unroll
  for(int mt=0;mt<2;mt++)
#pragma unroll
    for(int nt=0;nt<3;nt++) acc[mt][nt] = (f32x4){0.f,0.f,0.f,0.f};

  int sy[2], sx[2];
#pragma unroll
  for(int mt=0;mt<2;mt++){ int s = mh*32 + mt*16 + l15; sy[mt] = s>>3; sx[mt] = s&7; }
  const int co0 = coh*96 + (w&1)*48;
  const u16* wt = (const u16*)wb;
  int bco[3];
#pragma unroll
  for(int nt=0;nt<3;nt++) bco[nt] = (co0 + nt*16 + l15)*32 + q*8;

  for(int tap=0; tap<9; tap++){
    const int ky = tap/3, kx = tap%3;
    const u16* tb[2];
#pragma unroll
    for(int mt=0;mt<2;mt++)
      tb[mt] = &tile[((sy[mt]+ky)*10 + sx[mt]+kx)*CIPT + q*8];
#pragma unroll
    for(int c=0;c<6;c++){
      const u16* wp = wt + (size_t)(tap*6 + c)*WBLK;
      bf16x8 a[2], bbv[3];
#pragma unroll
      for(int mt=0;mt<2;mt++) a[mt] = *(const bf16x8*)(tb[mt] + c*32);
#pragma unroll
      for(int nt=0;nt<3;nt++) bbv[nt] = *(const bf16x8*)(wp + bco[nt]);
#pragma unroll
      for(int mt=0;mt<2;mt++)
#pragma unroll
        for(int nt=0;nt<3;nt++)
          acc[mt][nt] = __builtin_amdgcn_mfma_f32_16x16x32_bf16(a[mt], bbv[nt], acc[mt][nt], 0, 0, 0);
    }
  }
  epi_statsT(acc, sm, statsB, b, co0, l15, q, l, mh);
  epi_storeT(acc, tile, (u16*)out, b, oy0, ox0, Ho, Wo, t, w, coh, l15, q, mh);
}

// ---------------- s2 3x3 conv, co-split shape: direct-global A-frags ----------------

__global__ __launch_bounds__(256) void k_convs2T(const bf16* __restrict__ in,
        const bf16* __restrict__ wb, const u8* __restrict__ mk,
        bf16* __restrict__ out, int Ho, int Wo, float* __restrict__ statsB){
  __shared__ __align__(16) u16 obuf[64*104];
  __shared__ u8 sm[64];
  __shared__ int anyact;
  const int t = threadIdx.x;
  const int zb = blockIdx.z;
  const int b = zb & (NB-1);
  const int coh = zb >> 3;
  const int ox0 = blockIdx.x*8, oy0 = blockIdx.y*8;
  const int Hi = Ho*2, Wi = Wo*2;

  if(t == 0) anyact = 0;
  __syncthreads();
  if(t < 64){
    int r = t >> 3, c = t & 7;
    u8 mv = mk[(b*Ho + oy0 + r)*Wo + ox0 + c];
    sm[t] = mv;
    if(mv) anyact = 1;
  }
  __syncthreads();
  if(!anyact) return;

  const u16* inp = (const u16*)in;
  const int w = t >> 6;
  const int l = t & 63;
  const int l15 = l & 15, q = l >> 4;
  const int mh = w >> 1;
  f32x4 acc[2][3];
#pragma unroll
  for(int mt=0;mt<2;mt++)
#pragma unroll
    for(int nt=0;nt<3;nt++) acc[mt][nt] = (f32x4){0.f,0.f,0.f,0.f};

  int gyb[2], gxb[2];
#pragma unroll
  for(int mt=0;mt<2;mt++){
    int s = mh*32 + mt*16 + l15;
    gyb[mt] = (oy0 + (s>>3))*2 - 1;
    gxb[mt] = (ox0 + (s&7))*2 - 1;
  }
  const int co0 = coh*96 + (w&1)*48;
  const bf16x8 zro = {0,0,0,0,0,0,0,0};
  const u16* wt = (const u16*)wb;
  int bco[3];
#pragma unroll
  for(int nt=0;nt<3;nt++) bco[nt] = (co0 + nt*16 + l15)*32 + q*8;

  for(int tap=0; tap<9; tap++){
    const int ky = tap/3, kx = tap%3;
    const u16* ap[2]; bool av[2];
#pragma unroll
    for(int mt=0;mt<2;mt++){
      int gy = gyb[mt] + ky, gx = gxb[mt] + kx;
      av[mt] = (gy >= 0 && gy < Hi && gx >= 0 && gx < Wi);
      ap[mt] = inp + ((size_t)(b*Hi+gy)*Wi+gx)*CH + q*8;
    }
#pragma unroll
    for(int c=0;c<6;c++){
      const u16* wp = wt + (size_t)(tap*6 + c)*WBLK;
      bf16x8 a[2], bbv[3];
#pragma unroll
      for(int mt=0;mt<2;mt++) a[mt] = av[mt] ? *(const bf16x8*)(ap[mt] + c*32) : zro;
#pragma unroll
      for(int nt=0;nt<3;nt++) bbv[nt] = *(const bf16x8*)(wp + bco[nt]);
#pragma unroll
      for(int mt=0;mt<2;mt++)
#pragma unroll
        for(int nt=0;nt<3;nt++)
          acc[mt][nt] = __builtin_amdgcn_mfma_f32_16x16x32_bf16(a[mt], bbv[nt], acc[mt][nt], 0, 0, 0);
    }
  }
  epi_statsT(acc, sm, statsB, b, co0, l15, q, l, mh);
  epi_storeT(acc, obuf, (u16*)out, b, oy0, ox0, Ho, Wo, t, w, coh, l15, q, mh);
}

// ---------------- stage-0 (256->128 s2): 16x8 tile, fused MFMA stem, 6x32-ci passes ----------------
#define CIP0 36
#define NS0 561   // 33 rows x 17 cols input halo sites
__global__ __launch_bounds__(256) void k_conv0m(const float* __restrict__ im,
        const float* __restrict__ swf, const u8* __restrict__ m0,
        const bf16* __restrict__ wb, const u8* __restrict__ mk,
        bf16* __restrict__ out, float* __restrict__ statsB){
  __shared__ __align__(16) u16 tile[NS0*CIP0];   // 40392 B; obuf (13568 B) aliased
  __shared__ __align__(16) u16 bfr[576*8];       // 9216 B packed site B-frags
  __shared__ u8 sm[128];
  __shared__ int anyact;
  const int t = threadIdx.x;
  const int b = blockIdx.z;
  const int ox0 = blockIdx.x*8, oy0 = blockIdx.y*16;

  if(t == 0) anyact = 0;
  __syncthreads();
  if(t < 128){
    int r = t >> 3, c = t & 7;
    u8 mv = mk[(b*128 + oy0 + r)*128 + ox0 + c];
    sm[t] = mv;
    if(mv) anyact = 1;
  }
  __syncthreads();
  if(!anyact) return;

  const int gy0 = oy0*2 - 1, gx0 = ox0*2 - 1;
  // pack site frags once: {r,g,b,1, rl,gl,bl,0} at active in-bounds sites, else 0
  for(int e=t; e<576; e+=256){
    u32 w0=0u, w1=0u, w2=0u, w3=0u;
    if(e < NS0){
      int y = e/17, x = e%17;
      int gy = gy0 + y, gx = gx0 + x;
      if(gy >= 0 && gy < 256 && gx >= 0 && gx < 256){
        int pi = gy*256 + gx;
        if(m0[b*65536 + pi]){
          float rm = im[(size_t)(b*3+0)*65536 + pi];
          float gm = im[(size_t)(b*3+1)*65536 + pi];
          float bm = im[(size_t)(b*3+2)*65536 + pi];
          float rh = u2f(f2bu(rm)), gh = u2f(f2bu(gm)), bh = u2f(f2bu(bm));
          w0 = pk2bf(rm, gm);      w1 = pk2bf(bm, 1.0f);
          w2 = pk2bf(rm-rh, gm-gh); w3 = pk2bf(bm-bh, 0.f);
        }
      }
    }
    *(uint4*)&bfr[e*8] = make_uint4(w0, w1, w2, w3);
  }
  // bfr ready after the first in-loop barrier

  const int w = t >> 6;
  const int l = t & 63;
  const int l15 = l & 15, q = l >> 4;
  const bf16x8 zf = {0,0,0,0,0,0,0,0};

  f32x4 acc[8][3];
#pragma unroll
  for(int mt=0;mt<8;mt++)
#pragma unroll
    for(int nt=0;nt<3;nt++) acc[mt][nt] = (f32x4){0.f,0.f,0.f,0.f};

  int siy[8], six[8];
#pragma unroll
  for(int mt=0;mt<8;mt++){ int s = mt*16 + l15; siy[mt] = (s>>3)*2; six[mt] = (s&7)*2; }
  const int co0 = w*48;
  const u16* wt = (const u16*)wb;
  int bco[3];
#pragma unroll
  for(int nt=0;nt<3;nt++) bco[nt] = (co0 + nt*16 + l15)*32 + q*8;

  for(int h=0; h<6; h++){
    __syncthreads();   // prev pass's conv reads of tile done (and bfr ready at h=0)
    // weight A-frags for this 32-channel pass
    bf16x8 af[2];
#pragma unroll
    for(int mtl=0;mtl<2;mtl++){
      af[mtl] = zf;
      if(q == 0){
        const float4 wv = *(const float4*)&swf[(h*32 + mtl*16 + l15)*4];
        u32 wlo = pk2bf(wv.x, wv.y);
        ((u32*)&af[mtl])[0] = wlo;
        ((u32*)&af[mtl])[1] = pk2bf(wv.z, wv.w);
        ((u32*)&af[mtl])[2] = wlo;
        ((u32*)&af[mtl])[3] = pk2bf(wv.z, 0.f);
      }
    }
    // stem via MFMA over 36 site-tiles (9 per wave); lane writes 4 ch of one site
#pragma unroll
    for(int i=0;i<9;i++){
      int nt = w + i*4;               // wave-uniform, 0..35
      int site = nt*16 + l15;
      bf16x8 bs = zf;
      if(q == 0) bs = *(const bf16x8*)&bfr[(site < 576 ? site : 575)*8];
#pragma unroll
      for(int mtl=0;mtl<2;mtl++){
        f32x4 d = __builtin_amdgcn_mfma_f32_16x16x32_bf16(af[mtl], bs,
                        (f32x4){0.f,0.f,0.f,0.f}, 0, 0, 0);
        if(site < NS0){
          u32 lo = pk2bf(fmaxf(d[0],0.f), fmaxf(d[1],0.f));
          u32 hi = pk2bf(fmaxf(d[2],0.f), fmaxf(d[3],0.f));
          *(uint2*)&tile[site*CIP0 + mtl*16 + q*4] = make_uint2(lo, hi);
        }
      }
    }
    __syncthreads();
    // conv MFMA over this pass's 32 input channels: one K=32 step per tap
    for(int tap=0; tap<9; tap++){
      const int ky = tap/3, kx = tap%3;
      const u16* wp = wt + (size_t)(tap*6 + h)*WBLK;
      bf16x8 a[8], bbv[3];
#pragma unroll
      for(int mt=0;mt<8;mt++)
        a[mt] = *(const bf16x8*)&tile[((siy[mt]+ky)*17 + six[mt]+kx)*CIP0 + q*8];
#pragma unroll
      for(int nt=0;nt<3;nt++) bbv[nt] = *(const bf16x8*)(wp + bco[nt]);
#pragma unroll
      for(int mt=0;mt<8;mt++)
#pragma unroll
        for(int nt=0;nt<3;nt++)
          acc[mt][nt] = __builtin_amdgcn_mfma_f32_16x16x32_bf16(a[mt], bbv[nt], acc[mt][nt], 0, 0, 0);
    }
  }
  epi_stats8(acc, sm, statsB, b, co0, l15, q, l);
  epi_store_q(acc, tile, (u16*)out, b, oy0, ox0, 128, 128, t, co0, l15, q, 0);
  epi_store_q(acc, tile, (u16*)out, b, oy0, ox0, 128, 128, t, co0, l15, q, 1);
  epi_store_q(acc, tile, (u16*)out, b, oy0, ox0, 128, 128, t, co0, l15, q, 2);
  epi_store_q(acc, tile, (u16*)out, b, oy0, ox0, 128, 128, t, co0, l15, q, 3);
}

// ---------------- residual combine: X = relu(affD(D)*m + affB(B)*m), 8 elems/thread ----------------

__global__ __launch_bounds__(256) void k_resid(const bf16* __restrict__ xD,
        const bf16* __restrict__ xB, const u8* __restrict__ m,
        const float* __restrict__ stD, const float* __restrict__ gD, const float* __restrict__ bD,
        const float* __restrict__ stB, const float* __restrict__ gB, const float* __restrict__ bB,
        const float* __restrict__ cnt, bf16* __restrict__ out, int sites){
  __shared__ __align__(16) float scD[CH], shD[CH], scB[CH], shB[CH];
  const int t = threadIdx.x;
  build_ss(stD, gD, bD, cnt, scD, shD, t);
  build_ss(stB, gB, bB, cnt, scB, shB, t);
  __syncthreads();
  int idx = blockIdx.x*256 + t;
  int total = sites*24;           // 24 groups of 8 channels per site
  if(idx >= total) return;
  int si = idx/24; int c0 = (idx%24)*8;
  float mv = (float)m[si];
  const u16* pd = (const u16*)xD + (size_t)si*CH + c0;
  const u16* pb = (const u16*)xB + (size_t)si*CH + c0;
  uint4 vd = *(const uint4*)pd;
  uint4 vb = *(const uint4*)pb;
  u16* dd = (u16*)&vd; u16* db = (u16*)&vb;
  uint4 vo;
#pragma unroll
  for(int j=0;j<4;j++){
    int c = c0 + j*2;
    float f0 = (u2f(dd[j*2  ])*scD[c  ] + shD[c  ])*mv + (u2f(db[j*2  ])*scB[c  ] + shB[c  ])*mv;
    float f1 = (u2f(dd[j*2+1])*scD[c+1] + shD[c+1])*mv + (u2f(db[j*2+1])*scB[c+1] + shB[c+1])*mv;
    ((u32*)&vo)[j] = pk2bf(fmaxf(f0, 0.f), fmaxf(f1, 0.f));
  }
  *(uint4*)((u16*)out + (size_t)si*CH + c0) = vo;
}

// ---------------- final 1x1 conv as MFMA with fused per-batch stats ----------------
// block = (batch b, 64 consecutive sites); X is zero at inactive sites so raw conv is exact.

__global__ __launch_bounds__(256) void k_finalm(const bf16* __restrict__ in,
        const bf16* __restrict__ wb, const u8* __restrict__ m4,
        bf16* __restrict__ out, float* __restrict__ statsB){
  __shared__ __align__(16) u16 obuf[64*212];
  __shared__ u8 sm[64];
  __shared__ int anyact;
  const int t = threadIdx.x;
  const int b = blockIdx.z;
  const int base = blockIdx.x*64;

  if(t == 0) anyact = 0;
  __syncthreads();
  if(t < 64){
    u8 mv = m4[b*256 + base + t];
    sm[t] = mv;
    if(mv) anyact = 1;
  }
  __syncthreads();
  if(!anyact) return;

  const int w = t >> 6;
  const int l = t & 63;
  const int l15 = l & 15, q = l >> 4;
  const int co0 = w*48;
  f32x4 acc[4][3];
#pragma unroll
  for(int mt=0;mt<4;mt++)
#pragma unroll
    for(int nt=0;nt<3;nt++) acc[mt][nt] = (f32x4){0.f,0.f,0.f,0.f};

  const u16* inp = (const u16*)in + (size_t)(b*256 + base)*CH + q*8;
  const u16* wt = (const u16*)wb;
  int bco[3];
#pragma unroll
  for(int nt=0;nt<3;nt++) bco[nt] = (co0 + nt*16 + l15)*32 + q*8;
#pragma unroll
  for(int c=0;c<6;c++){
    const u16* wp = wt + (size_t)c*WBLK;
    bf16x8 a[4], bbv[3];
#pragma unroll
    for(int mt=0;mt<4;mt++)
      a[mt] = *(const bf16x8*)(inp + (size_t)(mt*16 + l15)*CH + c*32);
#pragma unroll
    for(int nt=0;nt<3;nt++) bbv[nt] = *(const bf16x8*)(wp + bco[nt]);
#pragma unroll
    for(int mt=0;mt<4;mt++)
#pragma unroll
      for(int nt=0;nt<3;nt++)
        acc[mt][nt] = __builtin_amdgcn_mfma_f32_16x16x32_bf16(a[mt], bbv[nt], acc[mt][nt], 0, 0, 0);
  }
  epi_stats(acc, sm, statsB, b, co0, l15, q, l);
  // Ho=32, Wo=8 maps (b, oy0=blk*8, rows r, cols sx) -> site b*256 + base + r*8 + sx
  epi_store(acc, obuf, (u16*)out, b, blockIdx.x*8, 0, 32, 8, t, co0, l15, q);
}

__global__ __launch_bounds__(256) void k_bnapply_out(const bf16* __restrict__ x,
        const u8* __restrict__ m, const float* __restrict__ stF,
        const float* __restrict__ g, const float* __restrict__ bb,
        const float* __restrict__ cnt, float* __restrict__ out){
  __shared__ __align__(16) float scs[CH], shs[CH];
  const int t = threadIdx.x;
  build_ss(stF, g, bb, cnt, scs, shs, t);
  __syncthreads();
  int i = blockIdx.x*256 + t;
  if(i >= NB*CH*256) return;
  int p = i % 256; int c = (i/256) % CH; int b = i/(256*CH);
  int si = b*256 + p;
  float v = bf2f(x[(size_t)si*CH + c])*scs[c] + shs[c];
  v *= (float)m[si];
  v = fmaxf(v, 0.f);
  out[i] = v;
}

// ---------------- tail ----------------

__global__ void k_tail(const int* __restrict__ mask, float* __restrict__ out){
  int i = blockIdx.x*blockDim.x + threadIdx.x;
  if(i < 2048){
    out[393216 + i] = (float)mask[i];
  } else if(i < 4096){
    int j = i - 2048;
    out[395264 + j] = (float)(j & 255);
  }
}

// ---------------- host orchestration ----------------

extern "C" void kernel_launch(void* const* d_in, const int* in_sizes, int n_in,
                              void* d_out, int out_size, void* d_ws, size_t ws_size,
                              hipStream_t stream){
  const float* images = (const float*)d_in[0];
  const int*   maskI  = (const int*)d_in[1];
  const float* stem_w = (const float*)d_in[2];
  const float* stem_g = (const float*)d_in[3];
  const float* stem_b = (const float*)d_in[4];
  const float* dw1 = (const float*)d_in[5];
  const float* dg1 = (const float*)d_in[6];
  const float* db1 = (const float*)d_in[7];
  const float* dw2 = (const float*)d_in[8];
  const float* dg2 = (const float*)d_in[9];
  const float* db2 = (const float*)d_in[10];
  const float* rw1 = (const float*)d_in[11];
  const float* rg1 = (const float*)d_in[12];
  const float* rb1 = (const float*)d_in[13];
  const float* rw2 = (const float*)d_in[14];
  const float* rg2 = (const float*)d_in[15];
  const float* rb2 = (const float*)d_in[16];
  const float* final_w = (const float*)d_in[17];
  const float* final_g = (const float*)d_in[18];
  const float* final_b = (const float*)d_in[19];
  float* outF = (float*)d_out;

  char* wsp = (char*)d_ws;
  auto alloc = [&](size_t bytes)->char*{
    char* p = wsp; wsp += (bytes + 255) & ~(size_t)255; return p;
  };
  bf16* S0 = (bf16*)alloc((size_t)NB*CH*16384*2);
  bf16* S1 = (bf16*)alloc((size_t)NB*CH*16384*2);
  bf16* S2 = (bf16*)alloc((size_t)NB*CH*16384*2);
  int Hs[5] = {256,128,64,32,16};
  u8* M[5];
  for(int l=0;l<5;l++) M[l] = (u8*)alloc((size_t)NB*Hs[l]*Hs[l]);
  bf16*  Wb16 = (bf16*)alloc((size_t)17*WSZ*2);      // 16 conv slots + final 1x1 slot
  float* swf = (float*)alloc(CH*4*4);
  float* statsB16 = (float*)alloc((size_t)17*NB*384*4);   // 16 conv slots + final slot
  float* statsF = (float*)alloc(384*4);                   // 9 image moments live here
  float* ssA   = (float*)alloc(2*CH*4);
  float* cnts  = (float*)alloc(8*4);
  size_t need = (size_t)(wsp - (char*)d_ws);

  if(ws_size < need){
    k_fill<<<(393216+255)/256, 256, 0, stream>>>(outF, 393216, 777.0f);
    k_tail<<<16, 256, 0, stream>>>(maskI, outF);
    return;
  }

  // ---- zero stats (ws poisoned every call) + repack all weights once ----
  int nz = 17*NB*384 + 384;
  k_zero<<<(nz+255)/256, 256, 0, stream>>>(statsB16, nz);
  k_zero<<<1, 32, 0, stream>>>(cnts, 8);
  k_repack16<<<(16*WSZ+255)/256, 256, 0, stream>>>(dw1, dw2, rw1, rw2, Wb16);
  k_repackF<<<(CH*CH+255)/256, 256, 0, stream>>>(final_w, Wb16 + (size_t)16*WSZ);

  // ---- mask pyramid + counts ----
  k_mask0<<<(NB*65536+255)/256, 256, 0, stream>>>(maskI, M[0]);
  for(int l=1;l<5;l++){
    int total = NB*Hs[l]*Hs[l];
    k_maskdown<<<(total+255)/256, 256, 0, stream>>>(M[l-1], M[l], Hs[l], Hs[l], Hs[l-1], Hs[l-1]);
  }
  for(int l=0;l<5;l++){
    int n = NB*Hs[l]*Hs[l];
    int blocks = (n + 256*64 - 1)/(256*64); if(blocks < 1) blocks = 1; if(blocks > 256) blocks = 256;
    k_count<<<blocks, 256, 0, stream>>>(M[l], n, cnts + l);
  }

  // ---- stem BN params via image moments + fold ----
  k_moments<<<512, 256, 0, stream>>>(images, M[0], statsF);
  k_stemfinal<<<1, CH, 0, stream>>>(statsF, cnts + 0, stem_w, stem_g, stem_b, ssA);
  k_fold<<<1, CH, 0, stream>>>(stem_w, ssA, swf);

  // ---- 4 stages ----
  bf16* X = nullptr;
  for(int i=0;i<4;i++){
    int Ho = Hs[i+1];
    int sites = NB*Ho*Ho;
    const u8* mk = M[i+1];
    const float* cnt = cnts + i + 1;
    bf16* A = S0;
    bf16* B = (i % 2 == 0) ? S1 : S2;
    bf16* C2 = (i == 0) ? S2 : X;
    const bf16* W0 = Wb16 + (size_t)(i*4+0)*WSZ;
    const bf16* W1 = Wb16 + (size_t)(i*4+1)*WSZ;
    const bf16* W2 = Wb16 + (size_t)(i*4+2)*WSZ;
    const bf16* W3 = Wb16 + (size_t)(i*4+3)*WSZ;
    float* st0 = statsB16 + (size_t)(i*4+0)*NB*384;
    float* st1 = statsB16 + (size_t)(i*4+1)*NB*384;
    float* st2 = statsB16 + (size_t)(i*4+2)*NB*384;
    float* st3 = statsB16 + (size_t)(i*4+3)*NB*384;

    dim3 gT(Ho/8, Ho/8, NB*2);          // co-split tail shape
    if(i == 0){
      k_conv0m<<<dim3(16, 8, NB), 256, 0, stream>>>(images, swf, M[0], W0, M[1], A, st0);
    } else {
      k_convs2T<<<gT, 256, 0, stream>>>(X, W0, mk, A, Ho, Ho, st0);
    }
    if(Ho >= 64){
      dim3 g2(Ho/8, Ho/16, NB);         // 16x8 high-intensity shape
      k_convm<1><<<g2, 256, 0, stream>>>(A, W1, mk, B, Ho, Ho,
          st0, dg1 + i*CH, db1 + i*CH, cnt, st1);
      k_convm<0><<<g2, 256, 0, stream>>>(B, W2, mk, A, Ho, Ho,
          st1, dg2 + i*CH, db2 + i*CH, cnt, st2);
      k_convm<1><<<g2, 256, 0, stream>>>(A, W3, mk, C2, Ho, Ho,
          st2, rg1 + i*CH, rb1 + i*CH, cnt, st3);
    } else {
      k_convmT<1><<<gT, 256, 0, stream>>>(A, W1, mk, B, Ho, Ho,
          st0, dg1 + i*CH, db1 + i*CH, cnt, st1);
      k_convmT<0><<<gT, 256, 0, stream>>>(B, W2, mk, A, Ho, Ho,
          st1, dg2 + i*CH, db2 + i*CH, cnt, st2);
      k_convmT<1><<<gT, 256, 0, stream>>>(A, W3, mk, C2, Ho, Ho,
          st2, rg1 + i*CH, rb1 + i*CH, cnt, st3);
    }
    k_resid<<<(sites*24 + 255)/256, 256, 0, stream>>>(C2, B, mk,
        st3, rg2 + i*CH, rb2 + i*CH,
        st1, dg2 + i*CH, db2 + i*CH, cnt, B, sites);
    X = B;
  }

  // ---- final 1x1 (MFMA, fused stats) + BN + ReLU -> d_out (f32 NCHW) ----
  float* stF = statsB16 + (size_t)16*NB*384;
  k_finalm<<<dim3(4, 1, NB), 256, 0, stream>>>(X, Wb16 + (size_t)16*WSZ, M[4], S0, stF);
  k_bnapply_out<<<(NB*CH*256 + 255)/256, 256, 0, stream>>>(S0, M[4], stF,
      final_g, final_b, cnts + 4, outF);

  // ---- tail ----
  k_tail<<<16, 256, 0, stream>>>(maskI, outF);
}

// Round 13
// 1041.141 us; speedup vs baseline: 1.4180x; 1.0316x over previous
//
#include <hip/hip_runtime.h>
#include <hip/hip_bf16.h>

typedef __hip_bfloat16 bf16;
typedef unsigned short u16;
typedef unsigned int u32;
typedef unsigned char u8;
typedef __attribute__((ext_vector_type(8))) short bf16x8;
typedef __attribute__((ext_vector_type(4))) float f32x4;

#define NB 8
#define CH 192
#define WSZ (CH*CH*9)
#define WBLK (CH*32)   // one [co][ci8] weight panel: 6144 u16 = 12 KB

// Activations channels-last: A[b][y][x][c], bf16. Convs write RAW outputs and
// accumulate masked per-batch BN stats into per-layer slots; consumers rebuild
// the affine in their prologue.
// Weights repacked to [slot][tap][ciblk32][co][ci8]: each wave's B-frag load is
// one contiguous coalesced 1-KB burst (validated: conv0m −15%, convm large win).
// T5: MFMA clusters wrapped in s_setprio(1)/(0) — ~3 independent blocks/CU at
// different phases (staging vs MFMA) gives the CU scheduler role diversity.
// NOTE (r7): T14 reg-prefetch of staging REGRESSED — compiler already covers it.
// NOTE (r10): mfma_32x32x16 convm REGRESSED (+400 µs) — B-stream duplicated
// across waves (4x VMEM) + 64-B lane stride. 16x16 per-wave-partitioned
// coalesced B-loads are load-bearing; keep them.

static __device__ __forceinline__ float bf2f(bf16 v){ return __bfloat162float(v); }
static __device__ __forceinline__ u16 f2bu(float f){
  union { bf16 h; u16 u; } cv; cv.h = __float2bfloat16(f); return cv.u;
}
static __device__ __forceinline__ float u2f(u16 u){
  union { bf16 h; u16 u; } cv; cv.u = u; return __bfloat162float(cv.h);
}
static __device__ __forceinline__ u32 pk2bf(float a, float b){
  union { __hip_bfloat162 h; u32 u; } cv;
  cv.h = __float22bfloat162_rn(make_float2(a, b));
  return cv.u;
}

// in-LDS per-channel affine rebuild from per-batch stats slot
static __device__ __forceinline__ void build_ss(const float* __restrict__ stIn,
        const float* __restrict__ g, const float* __restrict__ bb,
        const float* __restrict__ cnt, float* scs, float* shs, int t){
  if(t < CH){
    float s = 0.f, s2 = 0.f;
#pragma unroll
    for(int b=0;b<NB;b++){ s += stIn[b*384 + t]; s2 += stIn[b*384 + 192 + t]; }
    float n = fmaxf(*cnt, 1.0f);
    float mean = s/n;
    float var = fmaxf(s2/n - mean*mean, 0.f);
    float rstd = rsqrtf(var + 1e-5f);
    float sc = g[t]*rstd;
    scs[t] = sc;
    shs[t] = bb[t] - mean*sc;
  }
}

// 8-channel affine on a uint4 of bf16 (sc/sh 16B-aligned)
template<int RELU>
static __device__ __forceinline__ uint4 affine8(uint4 v, const float* scp, const float* shp){
  float4 sa = *(const float4*)(scp);
  float4 sb = *(const float4*)(scp+4);
  float4 ha = *(const float4*)(shp);
  float4 hb = *(const float4*)(shp+4);
  u16* pv = (u16*)&v;
  float f0, f1;
  f0 = u2f(pv[0])*sa.x + ha.x; f1 = u2f(pv[1])*sa.y + ha.y;
  if(RELU){ f0 = fmaxf(f0,0.f); f1 = fmaxf(f1,0.f); }
  ((u32*)&v)[0] = pk2bf(f0, f1);
  f0 = u2f(pv[2])*sa.z + ha.z; f1 = u2f(pv[3])*sa.w + ha.w;
  if(RELU){ f0 = fmaxf(f0,0.f); f1 = fmaxf(f1,0.f); }
  ((u32*)&v)[1] = pk2bf(f0, f1);
  f0 = u2f(pv[4])*sb.x + hb.x; f1 = u2f(pv[5])*sb.y + hb.y;
  if(RELU){ f0 = fmaxf(f0,0.f); f1 = fmaxf(f1,0.f); }
  ((u32*)&v)[2] = pk2bf(f0, f1);
  f0 = u2f(pv[6])*sb.z + hb.z; f1 = u2f(pv[7])*sb.w + hb.w;
  if(RELU){ f0 = fmaxf(f0,0.f); f1 = fmaxf(f1,0.f); }
  ((u32*)&v)[3] = pk2bf(f0, f1);
  return v;
}

// ---------------- utility kernels ----------------

__global__ void k_zero(float* p, int n){
  int i = blockIdx.x*blockDim.x + threadIdx.x;
  if(i < n) p[i] = 0.f;
}

__global__ void k_fill(float* p, int n, float v){
  int i = blockIdx.x*blockDim.x + threadIdx.x;
  if(i < n) p[i] = v;
}

__global__ void k_mask0(const int* __restrict__ mask, u8* __restrict__ m0){
  int i = blockIdx.x*blockDim.x + threadIdx.x;
  if(i >= NB*65536) return;
  int b = i >> 16; int p = i & 65535;
  int y = p >> 8, x = p & 255;
  int patch = (y >> 4)*16 + (x >> 4);
  m0[i] = (u8)(1 - mask[b*256 + patch]);
}

__global__ void k_maskdown(const u8* __restrict__ mi, u8* __restrict__ mo,
                           int Ho, int Wo, int Hi, int Wi){
  int i = blockIdx.x*blockDim.x + threadIdx.x;
  int total = NB*Ho*Wo; if(i >= total) return;
  int b = i/(Ho*Wo); int p = i%(Ho*Wo);
  int oy = p/Wo, ox = p%Wo;
  u8 v = 0;
  for(int ky=0; ky<3; ky++){
    int iy = oy*2 + ky - 1; if(iy < 0 || iy >= Hi) continue;
    for(int kx=0; kx<3; kx++){
      int ix = ox*2 + kx - 1; if(ix < 0 || ix >= Wi) continue;
      u8 t = mi[(b*Hi + iy)*Wi + ix]; if(t > v) v = t;
    }
  }
  mo[i] = v;
}

__global__ void k_count(const u8* __restrict__ m, int n, float* cnt){
  int i = blockIdx.x*blockDim.x + threadIdx.x;
  int stride = gridDim.x*blockDim.x;
  int local = 0;
  for(int j=i; j<n; j+=stride) local += m[j];
  for(int o=32; o>0; o>>=1) local += __shfl_down(local, o, 64);
  if((threadIdx.x & 63) == 0 && local) atomicAdd(cnt, (float)local);
}

// ---------------- stem BN stats via 9 masked image moments ----------------

__global__ __launch_bounds__(256) void k_moments(const float* __restrict__ im,
        const u8* __restrict__ m0, float* __restrict__ mom){
  float s[9];
#pragma unroll
  for(int k=0;k<9;k++) s[k]=0.f;
  int stride = gridDim.x*blockDim.x;
  for(int i = blockIdx.x*blockDim.x + threadIdx.x; i < NB*65536; i += stride){
    if(m0[i]){
      int b = i >> 16, p = i & 65535;
      float r = im[(size_t)(b*3+0)*65536 + p];
      float g = im[(size_t)(b*3+1)*65536 + p];
      float bl= im[(size_t)(b*3+2)*65536 + p];
      s[0]+=r;    s[1]+=g;    s[2]+=bl;
      s[3]+=r*r;  s[4]+=g*g;  s[5]+=bl*bl;
      s[6]+=r*g;  s[7]+=r*bl; s[8]+=g*bl;
    }
  }
#pragma unroll
  for(int k=0;k<9;k++){
    for(int o=32; o>0; o>>=1) s[k] += __shfl_down(s[k], o, 64);
  }
  __shared__ float sh[4][9];
  int w = threadIdx.x >> 6;
  if((threadIdx.x & 63) == 0){
#pragma unroll
    for(int k=0;k<9;k++) sh[w][k] = s[k];
  }
  __syncthreads();
  if(threadIdx.x < 9){
    float tt = sh[0][threadIdx.x] + sh[1][threadIdx.x] + sh[2][threadIdx.x] + sh[3][threadIdx.x];
    atomicAdd(&mom[threadIdx.x], tt);
  }
}

__global__ void k_stemfinal(const float* __restrict__ mom, const float* __restrict__ cnt,
        const float* __restrict__ sw, const float* __restrict__ g,
        const float* __restrict__ bb, float* __restrict__ ssA){
  int c = threadIdx.x; if(c >= CH) return;
  float n = fmaxf(*cnt, 1.0f);
  float m0=mom[0], m1=mom[1], m2=mom[2], m3=mom[3], m4=mom[4];
  float m5=mom[5], m6=mom[6], m7=mom[7], m8=mom[8];
  float w0 = sw[c*3+0], w1 = sw[c*3+1], w2 = sw[c*3+2];
  float mean = (w0*m0 + w1*m1 + w2*m2)/n;
  float e2 = (w0*w0*m3 + w1*w1*m4 + w2*w2*m5
            + 2.f*(w0*w1*m6 + w0*w2*m7 + w1*w2*m8))/n;
  float var = fmaxf(e2 - mean*mean, 0.f);
  float sc = g[c]*rsqrtf(var + 1e-5f);
  ssA[c] = sc;
  ssA[CH + c] = bb[c] - mean*sc;
}

__global__ void k_fold(const float* __restrict__ sw, const float* __restrict__ ssA,
                       float* __restrict__ swf){
  int c = threadIdx.x; if(c >= CH) return;
  float sc = ssA[c];
  swf[c*4+0] = sc*sw[c*3+0];
  swf[c*4+1] = sc*sw[c*3+1];
  swf[c*4+2] = sc*sw[c*3+2];
  swf[c*4+3] = ssA[CH+c];
}

// all 16 weight sets -> Wb16 slots [stage*4+sel][tap][ciblk32][co][ci8] bf16
// (coalesced layout: a wave B-frag (16 co x 32 ci) is one contiguous 1-KB block)
__global__ void k_repack16(const float* __restrict__ dw1, const float* __restrict__ dw2,
                           const float* __restrict__ rw1, const float* __restrict__ rw2,
                           bf16* __restrict__ wb){
  int i = blockIdx.x*blockDim.x + threadIdx.x;
  if(i >= 16*WSZ) return;
  int stage = i/(4*WSZ);
  int sel = (i/WSZ)%4;
  int r = i%WSZ;
  const float* w = (sel==0)?dw1 : (sel==1)?dw2 : (sel==2)?rw1 : rw2;
  float val = w[(size_t)stage*WSZ + r];
  int tap = r%9; int ci = (r/9)%CH; int co = r/(9*CH);
  wb[(size_t)(stage*4+sel)*WSZ + ((size_t)(tap*6 + (ci>>5))*CH + co)*32 + (ci&31)]
      = __float2bfloat16(val);
}

// final 1x1 weights -> bf16 [ciblk32][co][ci8]
__global__ void k_repackF(const float* __restrict__ fw, bf16* __restrict__ wb){
  int i = blockIdx.x*blockDim.x + threadIdx.x;
  if(i >= CH*CH) return;
  int co = i/CH, ci = i%CH;
  wb[((size_t)(ci>>5)*CH + co)*32 + (ci&31)] = __float2bfloat16(fw[i]);
}

// ---------------- 4-mt epilogues (64-site blocks, 192 co) ----------------

static __device__ __forceinline__ void epi_stats(f32x4 (&acc)[4][3], const u8* sm,
        float* __restrict__ statsB, int b, int co0, int l15, int q, int lane){
  float s[3], s2[3];
#pragma unroll
  for(int nt=0;nt<3;nt++){ s[nt]=0.f; s2[nt]=0.f; }
#pragma unroll
  for(int mt=0;mt<4;mt++){
#pragma unroll
    for(int r=0;r<4;r++){
      int site = mt*16 + q*4 + r;
      float mv = (float)sm[site];
#pragma unroll
      for(int nt=0;nt<3;nt++){
        float v = acc[mt][nt][r]*mv;
        s[nt] += v; s2[nt] += v*v;
      }
    }
  }
#pragma unroll
  for(int nt=0;nt<3;nt++){
    s[nt]  += __shfl_down(s[nt], 32, 64);  s[nt]  += __shfl_down(s[nt], 16, 64);
    s2[nt] += __shfl_down(s2[nt], 32, 64); s2[nt] += __shfl_down(s2[nt], 16, 64);
  }
  if(lane < 16){
#pragma unroll
    for(int nt=0;nt<3;nt++){
      int co = co0 + nt*16 + l15;
      atomicAdd(&statsB[b*384 + co], s[nt]);
      atomicAdd(&statsB[b*384 + 192 + co], s2[nt]);
    }
  }
}

// full 64-site epilogue (obuf needs 64*212 u16 = 27136 B)
static __device__ __forceinline__ void epi_store(f32x4 (&acc)[4][3], u16* obuf,
        u16* __restrict__ out, int b, int oy0, int ox0, int Ho, int Wo,
        int t, int co0, int l15, int q){
  __syncthreads();
#pragma unroll
  for(int mt=0;mt<4;mt++){
#pragma unroll
    for(int nt=0;nt<3;nt++){
      int co = co0 + nt*16 + l15;
#pragma unroll
      for(int r=0;r<4;r++){
        int site = mt*16 + q*4 + r;
        obuf[site*212 + co] = f2bu(acc[mt][nt][r]);
      }
    }
  }
  __syncthreads();
  for(int e=t; e<3072; e+=256){
    int r = e/384; int off = (e%384)*4;
    int sx = off/CH, co = off%CH;
    ushort4 v = *(const ushort4*)&obuf[(r*8+sx)*212 + co];
    *(ushort4*)(out + ((size_t)(b*Ho+oy0+r)*Wo + ox0)*CH + off) = v;
  }
}

// ---------------- 8-mt epilogues (128-site block tiles) ----------------

static __device__ __forceinline__ void epi_stats8(f32x4 (&acc)[8][3], const u8* sm,
        float* __restrict__ statsB, int b, int co0, int l15, int q, int lane){
  float s[3], s2[3];
#pragma unroll
  for(int nt=0;nt<3;nt++){ s[nt]=0.f; s2[nt]=0.f; }
#pragma unroll
  for(int mt=0;mt<8;mt++){
#pragma unroll
    for(int r=0;r<4;r++){
      int site = mt*16 + q*4 + r;
      float mv = (float)sm[site];
#pragma unroll
      for(int nt=0;nt<3;nt++){
        float v = acc[mt][nt][r]*mv;
        s[nt] += v; s2[nt] += v*v;
      }
    }
  }
#pragma unroll
  for(int nt=0;nt<3;nt++){
    s[nt]  += __shfl_down(s[nt], 32, 64);  s[nt]  += __shfl_down(s[nt], 16, 64);
    s2[nt] += __shfl_down(s2[nt], 32, 64); s2[nt] += __shfl_down(s2[nt], 16, 64);
  }
  if(lane < 16){
#pragma unroll
    for(int nt=0;nt<3;nt++){
      int co = co0 + nt*16 + l15;
      atomicAdd(&statsB[b*384 + co], s[nt]);
      atomicAdd(&statsB[b*384 + 192 + co], s2[nt]);
    }
  }
}

// quarter epilogue: 32 sites = acc rows qd*4..qd*4+3 (obuf needs 32*212 u16 = 13568 B)
static __device__ __forceinline__ void epi_store_q(f32x4 (&acc)[8][3], u16* obuf,
        u16* __restrict__ out, int b, int oy0, int ox0, int Ho, int Wo,
        int t, int co0, int l15, int q, int qd){
  __syncthreads();
#pragma unroll
  for(int mi=0; mi<2; mi++){
    int mt = qd*2 + mi;
#pragma unroll
    for(int nt=0;nt<3;nt++){
      int co = co0 + nt*16 + l15;
#pragma unroll
      for(int r=0;r<4;r++){
        int site = mi*16 + q*4 + r;   // local 0..31
        obuf[site*212 + co] = f2bu(acc[mt][nt][r]);
      }
    }
  }
  __syncthreads();
  for(int e=t; e<1536; e+=256){
    int r = e/384; int off = (e%384)*4;
    int sx = off/CH, co = off%CH;
    ushort4 v = *(const ushort4*)&obuf[(r*8+sx)*212 + co];
    *(ushort4*)(out + ((size_t)(b*Ho+oy0+qd*4+r)*Wo + ox0)*CH + off) = v;
  }
}

// ---------------- 2-mt epilogues (co-split: 64 sites x 96 co per block) ----------------

static __device__ __forceinline__ void epi_statsT(f32x4 (&acc)[2][3], const u8* sm,
        float* __restrict__ statsB, int b, int co0, int l15, int q, int lane, int mh){
  float s[3], s2[3];
#pragma unroll
  for(int nt=0;nt<3;nt++){ s[nt]=0.f; s2[nt]=0.f; }
#pragma unroll
  for(int mt=0;mt<2;mt++){
#pragma unroll
    for(int r=0;r<4;r++){
      int site = mh*32 + mt*16 + q*4 + r;
      float mv = (float)sm[site];
#pragma unroll
      for(int nt=0;nt<3;nt++){
        float v = acc[mt][nt][r]*mv;
        s[nt] += v; s2[nt] += v*v;
      }
    }
  }
#pragma unroll
  for(int nt=0;nt<3;nt++){
    s[nt]  += __shfl_down(s[nt], 32, 64);  s[nt]  += __shfl_down(s[nt], 16, 64);
    s2[nt] += __shfl_down(s2[nt], 32, 64); s2[nt] += __shfl_down(s2[nt], 16, 64);
  }
  if(lane < 16){
#pragma unroll
    for(int nt=0;nt<3;nt++){
      int co = co0 + nt*16 + l15;
      atomicAdd(&statsB[b*384 + co], s[nt]);
      atomicAdd(&statsB[b*384 + 192 + co], s2[nt]);
    }
  }
}

// obuf: 64 sites x 104 (96 co + pad); writes the block's 96-co slice
static __device__ __forceinline__ void epi_storeT(f32x4 (&acc)[2][3], u16* obuf,
        u16* __restrict__ out, int b, int oy0, int ox0, int Ho, int Wo,
        int t, int w, int coh, int l15, int q, int mh){
  __syncthreads();
#pragma unroll
  for(int mt=0;mt<2;mt++){
#pragma unroll
    for(int nt=0;nt<3;nt++){
      int col = (w&1)*48 + nt*16 + l15;
#pragma unroll
      for(int r=0;r<4;r++){
        int site = mh*32 + mt*16 + q*4 + r;
        obuf[site*104 + col] = f2bu(acc[mt][nt][r]);
      }
    }
  }
  __syncthreads();
  for(int e=t; e<1536; e+=256){
    int site = e/24; int grp = e%24;
    ushort4 v = *(const ushort4*)&obuf[site*104 + grp*4];
    *(ushort4*)(out + ((size_t)(b*Ho+oy0+(site>>3))*Wo + ox0+(site&7))*CH + coh*96 + grp*4) = v;
  }
}

// ---------------- s1 3x3 conv: 16x8 tile, 2x96-ci passes, 24-MFMA K-steps ----------------
#define CIP 104
template<int RELU>
__global__ __launch_bounds__(256) void k_convm(const bf16* __restrict__ in,
        const bf16* __restrict__ wb, const u8* __restrict__ mk,
        bf16* __restrict__ out, int Ho, int Wo,
        const float* __restrict__ stIn, const float* __restrict__ gIn,
        const float* __restrict__ bIn, const float* __restrict__ cnt,
        float* __restrict__ statsB){
  __shared__ __align__(16) u16 tile[180*CIP];   // 37440 B; obuf (13568 B) aliased
  __shared__ __align__(16) float scs[CH], shs[CH];
  __shared__ u8 sm[128];
  __shared__ u8 wmk[180];
  __shared__ int anyact;
  const int t = threadIdx.x;
  const int b = blockIdx.z;
  const int ox0 = blockIdx.x*8, oy0 = blockIdx.y*16;
  const int gy0 = oy0 - 1, gx0 = ox0 - 1;

  if(t == 0) anyact = 0;
  __syncthreads();
  if(t < 128){
    int r = t >> 3, c = t & 7;
    u8 mv = mk[(b*Ho + oy0 + r)*Wo + ox0 + c];
    sm[t] = mv;
    if(mv) anyact = 1;
  }
  for(int e=t; e<180; e+=256){
    int y = e/10, x = e%10;
    int gy = gy0 + y, gx = gx0 + x;
    u8 mv = 0;
    if(gy >= 0 && gy < Ho && gx >= 0 && gx < Wo) mv = mk[(b*Ho+gy)*Wo+gx];
    wmk[e] = mv;
  }
  __syncthreads();
  if(!anyact) return;

  build_ss(stIn, gIn, bIn, cnt, scs, shs, t);
  __syncthreads();

  const u16* inp = (const u16*)in;
  const int w = t >> 6;
  const int l = t & 63;
  const int l15 = l & 15, q = l >> 4;
  f32x4 acc[8][3];
#pragma unroll
  for(int mt=0;mt<8;mt++)
#pragma unroll
    for(int nt=0;nt<3;nt++) acc[mt][nt] = (f32x4){0.f,0.f,0.f,0.f};

  int sy[8], sx[8];
#pragma unroll
  for(int mt=0;mt<8;mt++){ int s = mt*16 + l15; sy[mt] = s>>3; sx[mt] = s&7; }
  const int co0 = w*48;
  const u16* wt = (const u16*)wb;
  int bco[3];
#pragma unroll
  for(int nt=0;nt<3;nt++) bco[nt] = (co0 + nt*16 + l15)*32 + q*8;

  for(int p=0; p<2; p++){
    if(p) __syncthreads();            // pass-0 conv reads of tile done
    const int cb = p*96;
    for(int u=t; u<2160; u+=256){
      int site = u/12; int grp = u%12;
      int y = site/10, x = site%10;
      int gy = gy0 + y, gx = gx0 + x;
      uint4 v = {0u,0u,0u,0u};
      if(wmk[site]){
        v = *(const uint4*)(inp + ((size_t)(b*Ho+gy)*Wo+gx)*CH + cb + grp*8);
        v = affine8<RELU>(v, &scs[cb + grp*8], &shs[cb + grp*8]);
      }
      *(uint4*)&tile[site*CIP + grp*8] = v;
    }
    __syncthreads();
    for(int tap=0; tap<9; tap++){
      const int ky = tap/3, kx = tap%3;
      const u16* tb[8];
#pragma unroll
      for(int mt=0;mt<8;mt++)
        tb[mt] = &tile[((sy[mt]+ky)*10 + sx[mt]+kx)*CIP + q*8];
#pragma unroll
      for(int c=0;c<3;c++){
        const u16* wp = wt + (size_t)(tap*6 + p*3 + c)*WBLK;
        bf16x8 a[8], bbv[3];
#pragma unroll
        for(int mt=0;mt<8;mt++) a[mt] = *(const bf16x8*)(tb[mt] + c*32);
#pragma unroll
        for(int nt=0;nt<3;nt++) bbv[nt] = *(const bf16x8*)(wp + bco[nt]);
        __builtin_amdgcn_s_setprio(1);
#pragma unroll
        for(int mt=0;mt<8;mt++)
#pragma unroll
          for(int nt=0;nt<3;nt++)
            acc[mt][nt] = __builtin_amdgcn_mfma_f32_16x16x32_bf16(a[mt], bbv[nt], acc[mt][nt], 0, 0, 0);
        __builtin_amdgcn_s_setprio(0);
      }
    }
  }
  epi_stats8(acc, sm, statsB, b, co0, l15, q, l);
  epi_store_q(acc, tile, (u16*)out, b, oy0, ox0, Ho, Wo, t, co0, l15, q, 0);
  epi_store_q(acc, tile, (u16*)out, b, oy0, ox0, Ho, Wo, t, co0, l15, q, 1);
  epi_store_q(acc, tile, (u16*)out, b, oy0, ox0, Ho, Wo, t, co0, l15, q, 2);
  epi_store_q(acc, tile, (u16*)out, b, oy0, ox0, Ho, Wo, t, co0, l15, q, 3);
}

// ---------------- s1 3x3 conv, co-split tail shape: 8x8 tile, 64 sites x 96 co ----------------
#define CIPT 200
template<int RELU>
__global__ __launch_bounds__(256) void k_convmT(const bf16* __restrict__ in,
        const bf16* __restrict__ wb, const u8* __restrict__ mk,
        bf16* __restrict__ out, int Ho, int Wo,
        const float* __restrict__ stIn, const float* __restrict__ gIn,
        const float* __restrict__ bIn, const float* __restrict__ cnt,
        float* __restrict__ statsB){
  __shared__ __align__(16) u16 tile[100*CIPT];   // 40 KB; obuf (64*104*2 = 13312 B) aliased
  __shared__ __align__(16) float scs[CH], shs[CH];
  __shared__ u8 sm[64];
  __shared__ u8 wmk[100];
  __shared__ int anyact;
  const int t = threadIdx.x;
  const int zb = blockIdx.z;
  const int b = zb & (NB-1);
  const int coh = zb >> 3;            // 0/1: which 96-co half
  const int ox0 = blockIdx.x*8, oy0 = blockIdx.y*8;
  const int gy0 = oy0 - 1, gx0 = ox0 - 1;

  if(t == 0) anyact = 0;
  __syncthreads();
  if(t < 64){
    int r = t >> 3, c = t & 7;
    u8 mv = mk[(b*Ho + oy0 + r)*Wo + ox0 + c];
    sm[t] = mv;
    if(mv) anyact = 1;
  } else if(t < 164){
    int e = t - 64;
    int y = e/10, x = e%10;
    int gy = gy0 + y, gx = gx0 + x;
    u8 mv = 0;
    if(gy >= 0 && gy < Ho && gx >= 0 && gx < Wo) mv = mk[(b*Ho+gy)*Wo+gx];
    wmk[e] = mv;
  }
  __syncthreads();
  if(!anyact) return;

  build_ss(stIn, gIn, bIn, cnt, scs, shs, t);
  __syncthreads();

  const u16* inp = (const u16*)in;
  for(int u=t; u<2400; u+=256){
    int y = u/240; int rem = u%240; int x = rem/24; int cu = rem%24;
    int gy = gy0 + y, gx = gx0 + x;
    uint4 v = {0u,0u,0u,0u};
    if(wmk[y*10+x]){
      v = *(const uint4*)(inp + ((size_t)(b*Ho+gy)*Wo+gx)*CH + cu*8);
      v = affine8<RELU>(v, &scs[cu*8], &shs[cu*8]);
    }
    *(uint4*)&tile[(y*10+x)*CIPT + cu*8] = v;
  }
  __syncthreads();

  const int w = t >> 6;
  const int l = t & 63;
  const int l15 = l & 15, q = l >> 4;
  const int mh = w >> 1;              // site half: 0 -> sites 0..31, 1 -> 32..63
  f32x4 acc[2][3];
#pragma unroll
  for(int mt=0;mt<2;mt++)
#pragma unroll
    for(int nt=0;nt<3;nt++) acc[mt][nt] = (f32x4){0.f,0.f,0.f,0.f};

  int sy[2], sx[2];
#pragma unroll
  for(int mt=0;mt<2;mt++){ int s = mh*32 + mt*16 + l15; sy[mt] = s>>3; sx[mt] = s&7; }
  const int co0 = coh*96 + (w&1)*48;
  const u16* wt = (const u16*)wb;
  int bco[3];
#pragma unroll
  for(int nt=0;nt<3;nt++) bco[nt] = (co0 + nt*16 + l15)*32 + q*8;

  for(int tap=0; tap<9; tap++){
    const int ky = tap/3, kx = tap%3;
    const u16* tb[2];
#pragma unroll
    for(int mt=0;mt<2;mt++)
      tb[mt] = &tile[((sy[mt]+ky)*10 + sx[mt]+kx)*CIPT + q*8];
#pragma unroll
    for(int c=0;c<6;c++){
      const u16* wp = wt + (size_t)(tap*6 + c)*WBLK;
      bf16x8 a[2], bbv[3];
#pragma unroll
      for(int mt=0;mt<2;mt++) a[mt] = *(const bf16x8*)(tb[mt] + c*32);
#pragma unroll
      for(int nt=0;nt<3;nt++) bbv[nt] = *(const bf16x8*)(wp + bco[nt]);
      __builtin_amdgcn_s_setprio(1);
#pragma unroll
      for(int mt=0;mt<2;mt++)
#pragma unroll
        for(int nt=0;nt<3;nt++)
          acc[mt][nt] = __builtin_amdgcn_mfma_f32_16x16x32_bf16(a[mt], bbv[nt], acc[mt][nt], 0, 0, 0);
      __builtin_amdgcn_s_setprio(0);
    }
  }
  epi_statsT(acc, sm, statsB, b, co0, l15, q, l, mh);
  epi_storeT(acc, tile, (u16*)out, b, oy0, ox0, Ho, Wo, t, w, coh, l15, q, mh);
}

// ---------------- s2 3x3 conv, co-split shape: direct-global A-frags ----------------

__global__ __launch_bounds__(256) void k_convs2T(const bf16* __restrict__ in,
        const bf16* __restrict__ wb, const u8* __restrict__ mk,
        bf16* __restrict__ out, int Ho, int Wo, float* __restrict__ statsB){
  __shared__ __align__(16) u16 obuf[64*104];
  __shared__ u8 sm[64];
  __shared__ int anyact;
  const int t = threadIdx.x;
  const int zb = blockIdx.z;
  const int b = zb & (NB-1);
  const int coh = zb >> 3;
  const int ox0 = blockIdx.x*8, oy0 = blockIdx.y*8;
  const int Hi = Ho*2, Wi = Wo*2;

  if(t == 0) anyact = 0;
  __syncthreads();
  if(t < 64){
    int r = t >> 3, c = t & 7;
    u8 mv = mk[(b*Ho + oy0 + r)*Wo + ox0 + c];
    sm[t] = mv;
    if(mv) anyact = 1;
  }
  __syncthreads();
  if(!anyact) return;

  const u16* inp = (const u16*)in;
  const int w = t >> 6;
  const int l = t & 63;
  const int l15 = l & 15, q = l >> 4;
  const int mh = w >> 1;
  f32x4 acc[2][3];
#pragma unroll
  for(int mt=0;mt<2;mt++)
#pragma unroll
    for(int nt=0;nt<3;nt++) acc[mt][nt] = (f32x4){0.f,0.f,0.f,0.f};

  int gyb[2], gxb[2];
#pragma unroll
  for(int mt=0;mt<2;mt++){
    int s = mh*32 + mt*16 + l15;
    gyb[mt] = (oy0 + (s>>3))*2 - 1;
    gxb[mt] = (ox0 + (s&7))*2 - 1;
  }
  const int co0 = coh*96 + (w&1)*48;
  const bf16x8 zro = {0,0,0,0,0,0,0,0};
  const u16* wt = (const u16*)wb;
  int bco[3];
#pragma unroll
  for(int nt=0;nt<3;nt++) bco[nt] = (co0 + nt*16 + l15)*32 + q*8;

  for(int tap=0; tap<9; tap++){
    const int ky = tap/3, kx = tap%3;
    const u16* ap[2]; bool av[2];
#pragma unroll
    for(int mt=0;mt<2;mt++){
      int gy = gyb[mt] + ky, gx = gxb[mt] + kx;
      av[mt] = (gy >= 0 && gy < Hi && gx >= 0 && gx < Wi);
      ap[mt] = inp + ((size_t)(b*Hi+gy)*Wi+gx)*CH + q*8;
    }
#pragma unroll
    for(int c=0;c<6;c++){
      const u16* wp = wt + (size_t)(tap*6 + c)*WBLK;
      bf16x8 a[2], bbv[3];
#pragma unroll
      for(int mt=0;mt<2;mt++) a[mt] = av[mt] ? *(const bf16x8*)(ap[mt] + c*32) : zro;
#pragma unroll
      for(int nt=0;nt<3;nt++) bbv[nt] = *(const bf16x8*)(wp + bco[nt]);
      __builtin_amdgcn_s_setprio(1);
#pragma unroll
      for(int mt=0;mt<2;mt++)
#pragma unroll
        for(int nt=0;nt<3;nt++)
          acc[mt][nt] = __builtin_amdgcn_mfma_f32_16x16x32_bf16(a[mt], bbv[nt], acc[mt][nt], 0, 0, 0);
      __builtin_amdgcn_s_setprio(0);
    }
  }
  epi_statsT(acc, sm, statsB, b, co0, l15, q, l, mh);
  epi_storeT(acc, obuf, (u16*)out, b, oy0, ox0, Ho, Wo, t, w, coh, l15, q, mh);
}

// ---------------- stage-0 (256->128 s2): 16x8 tile, fused MFMA stem, 6x32-ci passes ----------------
#define CIP0 36
#define NS0 561   // 33 rows x 17 cols input halo sites
__global__ __launch_bounds__(256) void k_conv0m(const float* __restrict__ im,
        const float* __restrict__ swf, const u8* __restrict__ m0,
        const bf16* __restrict__ wb, const u8* __restrict__ mk,
        bf16* __restrict__ out, float* __restrict__ statsB){
  __shared__ __align__(16) u16 tile[NS0*CIP0];   // 40392 B; obuf (13568 B) aliased
  __shared__ __align__(16) u16 bfr[576*8];       // 9216 B packed site B-frags
  __shared__ u8 sm[128];
  __shared__ int anyact;
  const int t = threadIdx.x;
  const int b = blockIdx.z;
  const int ox0 = blockIdx.x*8, oy0 = blockIdx.y*16;

  if(t == 0) anyact = 0;
  __syncthreads();
  if(t < 128){
    int r = t >> 3, c = t & 7;
    u8 mv = mk[(b*128 + oy0 + r)*128 + ox0 + c];
    sm[t] = mv;
    if(mv) anyact = 1;
  }
  __syncthreads();
  if(!anyact) return;

  const int gy0 = oy0*2 - 1, gx0 = ox0*2 - 1;
  // pack site frags once: {r,g,b,1, rl,gl,bl,0} at active in-bounds sites, else 0
  for(int e=t; e<576; e+=256){
    u32 w0=0u, w1=0u, w2=0u, w3=0u;
    if(e < NS0){
      int y = e/17, x = e%17;
      int gy = gy0 + y, gx = gx0 + x;
      if(gy >= 0 && gy < 256 && gx >= 0 && gx < 256){
        int pi = gy*256 + gx;
        if(m0[b*65536 + pi]){
          float rm = im[(size_t)(b*3+0)*65536 + pi];
          float gm = im[(size_t)(b*3+1)*65536 + pi];
          float bm = im[(size_t)(b*3+2)*65536 + pi];
          float rh = u2f(f2bu(rm)), gh = u2f(f2bu(gm)), bh = u2f(f2bu(bm));
          w0 = pk2bf(rm, gm);      w1 = pk2bf(bm, 1.0f);
          w2 = pk2bf(rm-rh, gm-gh); w3 = pk2bf(bm-bh, 0.f);
        }
      }
    }
    *(uint4*)&bfr[e*8] = make_uint4(w0, w1, w2, w3);
  }
  // bfr ready after the first in-loop barrier

  const int w = t >> 6;
  const int l = t & 63;
  const int l15 = l & 15, q = l >> 4;
  const bf16x8 zf = {0,0,0,0,0,0,0,0};

  f32x4 acc[8][3];
#pragma unroll
  for(int mt=0;mt<8;mt++)
#pragma unroll
    for(int nt=0;nt<3;nt++) acc[mt][nt] = (f32x4){0.f,0.f,0.f,0.f};

  int siy[8], six[8];
#pragma unroll
  for(int mt=0;mt<8;mt++){ int s = mt*16 + l15; siy[mt] = (s>>3)*2; six[mt] = (s&7)*2; }
  const int co0 = w*48;
  const u16* wt = (const u16*)wb;
  int bco[3];
#pragma unroll
  for(int nt=0;nt<3;nt++) bco[nt] = (co0 + nt*16 + l15)*32 + q*8;

  for(int h=0; h<6; h++){
    __syncthreads();   // prev pass's conv reads of tile done (and bfr ready at h=0)
    // weight A-frags for this 32-channel pass
    bf16x8 af[2];
#pragma unroll
    for(int mtl=0;mtl<2;mtl++){
      af[mtl] = zf;
      if(q == 0){
        const float4 wv = *(const float4*)&swf[(h*32 + mtl*16 + l15)*4];
        u32 wlo = pk2bf(wv.x, wv.y);
        ((u32*)&af[mtl])[0] = wlo;
        ((u32*)&af[mtl])[1] = pk2bf(wv.z, wv.w);
        ((u32*)&af[mtl])[2] = wlo;
        ((u32*)&af[mtl])[3] = pk2bf(wv.z, 0.f);
      }
    }
    // stem via MFMA over 36 site-tiles (9 per wave); lane writes 4 ch of one site
#pragma unroll
    for(int i=0;i<9;i++){
      int nt = w + i*4;               // wave-uniform, 0..35
      int site = nt*16 + l15;
      bf16x8 bs = zf;
      if(q == 0) bs = *(const bf16x8*)&bfr[(site < 576 ? site : 575)*8];
#pragma unroll
      for(int mtl=0;mtl<2;mtl++){
        f32x4 d = __builtin_amdgcn_mfma_f32_16x16x32_bf16(af[mtl], bs,
                        (f32x4){0.f,0.f,0.f,0.f}, 0, 0, 0);
        if(site < NS0){
          u32 lo = pk2bf(fmaxf(d[0],0.f), fmaxf(d[1],0.f));
          u32 hi = pk2bf(fmaxf(d[2],0.f), fmaxf(d[3],0.f));
          *(uint2*)&tile[site*CIP0 + mtl*16 + q*4] = make_uint2(lo, hi);
        }
      }
    }
    __syncthreads();
    // conv MFMA over this pass's 32 input channels: one K=32 step per tap
    for(int tap=0; tap<9; tap++){
      const int ky = tap/3, kx = tap%3;
      const u16* wp = wt + (size_t)(tap*6 + h)*WBLK;
      bf16x8 a[8], bbv[3];
#pragma unroll
      for(int mt=0;mt<8;mt++)
        a[mt] = *(const bf16x8*)&tile[((siy[mt]+ky)*17 + six[mt]+kx)*CIP0 + q*8];
#pragma unroll
      for(int nt=0;nt<3;nt++) bbv[nt] = *(const bf16x8*)(wp + bco[nt]);
      __builtin_amdgcn_s_setprio(1);
#pragma unroll
      for(int mt=0;mt<8;mt++)
#pragma unroll
        for(int nt=0;nt<3;nt++)
          acc[mt][nt] = __builtin_amdgcn_mfma_f32_16x16x32_bf16(a[mt], bbv[nt], acc[mt][nt], 0, 0, 0);
      __builtin_amdgcn_s_setprio(0);
    }
  }
  epi_stats8(acc, sm, statsB, b, co0, l15, q, l);
  epi_store_q(acc, tile, (u16*)out, b, oy0, ox0, 128, 128, t, co0, l15, q, 0);
  epi_store_q(acc, tile, (u16*)out, b, oy0, ox0, 128, 128, t, co0, l15, q, 1);
  epi_store_q(acc, tile, (u16*)out, b, oy0, ox0, 128, 128, t, co0, l15, q, 2);
  epi_store_q(acc, tile, (u16*)out, b, oy0, ox0, 128, 128, t, co0, l15, q, 3);
}

// ---------------- residual combine: X = relu(affD(D)*m + affB(B)*m), 8 elems/thread ----------------

__global__ __launch_bounds__(256) void k_resid(const bf16* __restrict__ xD,
        const bf16* __restrict__ xB, const u8* __restrict__ m,
        const float* __restrict__ stD, const float* __restrict__ gD, const float* __restrict__ bD,
        const float* __restrict__ stB, const float* __restrict__ gB, const float* __restrict__ bB,
        const float* __restrict__ cnt, bf16* __restrict__ out, int sites){
  __shared__ __align__(16) float scD[CH], shD[CH], scB[CH], shB[CH];
  const int t = threadIdx.x;
  build_ss(stD, gD, bD, cnt, scD, shD, t);
  build_ss(stB, gB, bB, cnt, scB, shB, t);
  __syncthreads();
  int idx = blockIdx.x*256 + t;
  int total = sites*24;           // 24 groups of 8 channels per site
  if(idx >= total) return;
  int si = idx/24; int c0 = (idx%24)*8;
  float mv = (float)m[si];
  const u16* pd = (const u16*)xD + (size_t)si*CH + c0;
  const u16* pb = (const u16*)xB + (size_t)si*CH + c0;
  uint4 vd = *(const uint4*)pd;
  uint4 vb = *(const uint4*)pb;
  u16* dd = (u16*)&vd; u16* db = (u16*)&vb;
  uint4 vo;
#pragma unroll
  for(int j=0;j<4;j++){
    int c = c0 + j*2;
    float f0 = (u2f(dd[j*2  ])*scD[c  ] + shD[c  ])*mv + (u2f(db[j*2  ])*scB[c  ] + shB[c  ])*mv;
    float f1 = (u2f(dd[j*2+1])*scD[c+1] + shD[c+1])*mv + (u2f(db[j*2+1])*scB[c+1] + shB[c+1])*mv;
    ((u32*)&vo)[j] = pk2bf(fmaxf(f0, 0.f), fmaxf(f1, 0.f));
  }
  *(uint4*)((u16*)out + (size_t)si*CH + c0) = vo;
}

// ---------------- final 1x1 conv as MFMA with fused per-batch stats ----------------
// block = (batch b, 64 consecutive sites); X is zero at inactive sites so raw conv is exact.

__global__ __launch_bounds__(256) void k_finalm(const bf16* __restrict__ in,
        const bf16* __restrict__ wb, const u8* __restrict__ m4,
        bf16* __restrict__ out, float* __restrict__ statsB){
  __shared__ __align__(16) u16 obuf[64*212];
  __shared__ u8 sm[64];
  __shared__ int anyact;
  const int t = threadIdx.x;
  const int b = blockIdx.z;
  const int base = blockIdx.x*64;

  if(t == 0) anyact = 0;
  __syncthreads();
  if(t < 64){
    u8 mv = m4[b*256 + base + t];
    sm[t] = mv;
    if(mv) anyact = 1;
  }
  __syncthreads();
  if(!anyact) return;

  const int w = t >> 6;
  const int l = t & 63;
  const int l15 = l & 15, q = l >> 4;
  const int co0 = w*48;
  f32x4 acc[4][3];
#pragma unroll
  for(int mt=0;mt<4;mt++)
#pragma unroll
    for(int nt=0;nt<3;nt++) acc[mt][nt] = (f32x4){0.f,0.f,0.f,0.f};

  const u16* inp = (const u16*)in + (size_t)(b*256 + base)*CH + q*8;
  const u16* wt = (const u16*)wb;
  int bco[3];
#pragma unroll
  for(int nt=0;nt<3;nt++) bco[nt] = (co0 + nt*16 + l15)*32 + q*8;
#pragma unroll
  for(int c=0;c<6;c++){
    const u16* wp = wt + (size_t)c*WBLK;
    bf16x8 a[4], bbv[3];
#pragma unroll
    for(int mt=0;mt<4;mt++)
      a[mt] = *(const bf16x8*)(inp + (size_t)(mt*16 + l15)*CH + c*32);
#pragma unroll
    for(int nt=0;nt<3;nt++) bbv[nt] = *(const bf16x8*)(wp + bco[nt]);
    __builtin_amdgcn_s_setprio(1);
#pragma unroll
    for(int mt=0;mt<4;mt++)
#pragma unroll
      for(int nt=0;nt<3;nt++)
        acc[mt][nt] = __builtin_amdgcn_mfma_f32_16x16x32_bf16(a[mt], bbv[nt], acc[mt][nt], 0, 0, 0);
    __builtin_amdgcn_s_setprio(0);
  }
  epi_stats(acc, sm, statsB, b, co0, l15, q, l);
  // Ho=32, Wo=8 maps (b, oy0=blk*8, rows r, cols sx) -> site b*256 + base + r*8 + sx
  epi_store(acc, obuf, (u16*)out, b, blockIdx.x*8, 0, 32, 8, t, co0, l15, q);
}

__global__ __launch_bounds__(256) void k_bnapply_out(const bf16* __restrict__ x,
        const u8* __restrict__ m, const float* __restrict__ stF,
        const float* __restrict__ g, const float* __restrict__ bb,
        const float* __restrict__ cnt, float* __restrict__ out){
  __shared__ __align__(16) float scs[CH], shs[CH];
  const int t = threadIdx.x;
  build_ss(stF, g, bb, cnt, scs, shs, t);
  __syncthreads();
  int i = blockIdx.x*256 + t;
  if(i >= NB*CH*256) return;
  int p = i % 256; int c = (i/256) % CH; int b = i/(256*CH);
  int si = b*256 + p;
  float v = bf2f(x[(size_t)si*CH + c])*scs[c] + shs[c];
  v *= (float)m[si];
  v = fmaxf(v, 0.f);
  out[i] = v;
}

// ---------------- tail ----------------

__global__ void k_tail(const int* __restrict__ mask, float* __restrict__ out){
  int i = blockIdx.x*blockDim.x + threadIdx.x;
  if(i < 2048){
    out[393216 + i] = (float)mask[i];
  } else if(i < 4096){
    int j = i - 2048;
    out[395264 + j] = (float)(j & 255);
  }
}

// ---------------- host orchestration ----------------

extern "C" void kernel_launch(void* const* d_in, const int* in_sizes, int n_in,
                              void* d_out, int out_size, void* d_ws, size_t ws_size,
                              hipStream_t stream){
  const float* images = (const float*)d_in[0];
  const int*   maskI  = (const int*)d_in[1];
  const float* stem_w = (const float*)d_in[2];
  const float* stem_g = (const float*)d_in[3];
  const float* stem_b = (const float*)d_in[4];
  const float* dw1 = (const float*)d_in[5];
  const float* dg1 = (const float*)d_in[6];
  const float* db1 = (const float*)d_in[7];
  const float* dw2 = (const float*)d_in[8];
  const float* dg2 = (const float*)d_in[9];
  const float* db2 = (const float*)d_in[10];
  const float* rw1 = (const float*)d_in[11];
  const float* rg1 = (const float*)d_in[12];
  const float* rb1 = (const float*)d_in[13];
  const float* rw2 = (const float*)d_in[14];
  const float* rg2 = (const float*)d_in[15];
  const float* rb2 = (const float*)d_in[16];
  const float* final_w = (const float*)d_in[17];
  const float* final_g = (const float*)d_in[18];
  const float* final_b = (const float*)d_in[19];
  float* outF = (float*)d_out;

  char* wsp = (char*)d_ws;
  auto alloc = [&](size_t bytes)->char*{
    char* p = wsp; wsp += (bytes + 255) & ~(size_t)255; return p;
  };
  bf16* S0 = (bf16*)alloc((size_t)NB*CH*16384*2);
  bf16* S1 = (bf16*)alloc((size_t)NB*CH*16384*2);
  bf16* S2 = (bf16*)alloc((size_t)NB*CH*16384*2);
  int Hs[5] = {256,128,64,32,16};
  u8* M[5];
  for(int l=0;l<5;l++) M[l] = (u8*)alloc((size_t)NB*Hs[l]*Hs[l]);
  bf16*  Wb16 = (bf16*)alloc((size_t)17*WSZ*2);      // 16 conv slots + final 1x1 slot
  float* swf = (float*)alloc(CH*4*4);
  float* statsB16 = (float*)alloc((size_t)17*NB*384*4);   // 16 conv slots + final slot
  float* statsF = (float*)alloc(384*4);                   // 9 image moments live here
  float* ssA   = (float*)alloc(2*CH*4);
  float* cnts  = (float*)alloc(8*4);
  size_t need = (size_t)(wsp - (char*)d_ws);

  if(ws_size < need){
    k_fill<<<(393216+255)/256, 256, 0, stream>>>(outF, 393216, 777.0f);
    k_tail<<<16, 256, 0, stream>>>(maskI, outF);
    return;
  }

  // ---- zero stats (ws poisoned every call) + repack all weights once ----
  int nz = 17*NB*384 + 384;
  k_zero<<<(nz+255)/256, 256, 0, stream>>>(statsB16, nz);
  k_zero<<<1, 32, 0, stream>>>(cnts, 8);
  k_repack16<<<(16*WSZ+255)/256, 256, 0, stream>>>(dw1, dw2, rw1, rw2, Wb16);
  k_repackF<<<(CH*CH+255)/256, 256, 0, stream>>>(final_w, Wb16 + (size_t)16*WSZ);

  // ---- mask pyramid + counts ----
  k_mask0<<<(NB*65536+255)/256, 256, 0, stream>>>(maskI, M[0]);
  for(int l=1;l<5;l++){
    int total = NB*Hs[l]*Hs[l];
    k_maskdown<<<(total+255)/256, 256, 0, stream>>>(M[l-1], M[l], Hs[l], Hs[l], Hs[l-1], Hs[l-1]);
  }
  for(int l=0;l<5;l++){
    int n = NB*Hs[l]*Hs[l];
    int blocks = (n + 256*64 - 1)/(256*64); if(blocks < 1) blocks = 1; if(blocks > 256) blocks = 256;
    k_count<<<blocks, 256, 0, stream>>>(M[l], n, cnts + l);
  }

  // ---- stem BN params via image moments + fold ----
  k_moments<<<512, 256, 0, stream>>>(images, M[0], statsF);
  k_stemfinal<<<1, CH, 0, stream>>>(statsF, cnts + 0, stem_w, stem_g, stem_b, ssA);
  k_fold<<<1, CH, 0, stream>>>(stem_w, ssA, swf);

  // ---- 4 stages ----
  bf16* X = nullptr;
  for(int i=0;i<4;i++){
    int Ho = Hs[i+1];
    int sites = NB*Ho*Ho;
    const u8* mk = M[i+1];
    const float* cnt = cnts + i + 1;
    bf16* A = S0;
    bf16* B = (i % 2 == 0) ? S1 : S2;
    bf16* C2 = (i == 0) ? S2 : X;
    const bf16* W0 = Wb16 + (size_t)(i*4+0)*WSZ;
    const bf16* W1 = Wb16 + (size_t)(i*4+1)*WSZ;
    const bf16* W2 = Wb16 + (size_t)(i*4+2)*WSZ;
    const bf16* W3 = Wb16 + (size_t)(i*4+3)*WSZ;
    float* st0 = statsB16 + (size_t)(i*4+0)*NB*384;
    float* st1 = statsB16 + (size_t)(i*4+1)*NB*384;
    float* st2 = statsB16 + (size_t)(i*4+2)*NB*384;
    float* st3 = statsB16 + (size_t)(i*4+3)*NB*384;

    dim3 gT(Ho/8, Ho/8, NB*2);          // co-split tail shape
    if(i == 0){
      k_conv0m<<<dim3(16, 8, NB), 256, 0, stream>>>(images, swf, M[0], W0, M[1], A, st0);
    } else {
      k_convs2T<<<gT, 256, 0, stream>>>(X, W0, mk, A, Ho, Ho, st0);
    }
    if(Ho >= 64){
      dim3 g2(Ho/8, Ho/16, NB);         // 16x8 high-intensity shape
      k_convm<1><<<g2, 256, 0, stream>>>(A, W1, mk, B, Ho, Ho,
          st0, dg1 + i*CH, db1 + i*CH, cnt, st1);
      k_convm<0><<<g2, 256, 0, stream>>>(B, W2, mk, A, Ho, Ho,
          st1, dg2 + i*CH, db2 + i*CH, cnt, st2);
      k_convm<1><<<g2, 256, 0, stream>>>(A, W3, mk, C2, Ho, Ho,
          st2, rg1 + i*CH, rb1 + i*CH, cnt, st3);
    } else {
      k_convmT<1><<<gT, 256, 0, stream>>>(A, W1, mk, B, Ho, Ho,
          st0, dg1 + i*CH, db1 + i*CH, cnt, st1);
      k_convmT<0><<<gT, 256, 0, stream>>>(B, W2, mk, A, Ho, Ho,
          st1, dg2 + i*CH, db2 + i*CH, cnt, st2);
      k_convmT<1><<<gT, 256, 0, stream>>>(A, W3, mk, C2, Ho, Ho,
          st2, rg1 + i*CH, rb1 + i*CH, cnt, st3);
    }
    k_resid<<<(sites*24 + 255)/256, 256, 0, stream>>>(C2, B, mk,
        st3, rg2 + i*CH, rb2 + i*CH,
        st1, dg2 + i*CH, db2 + i*CH, cnt, B, sites);
    X = B;
  }

  // ---- final 1x1 (MFMA, fused stats) + BN + ReLU -> d_out (f32 NCHW) ----
  float* stF = statsB16 + (size_t)16*NB*384;
  k_finalm<<<dim3(4, 1, NB), 256, 0, stream>>>(X, Wb16 + (size_t)16*WSZ, M[4], S0, stF);
  k_bnapply_out<<<(NB*CH*256 + 255)/256, 256, 0, stream>>>(S0, M[4], stF,
      final_g, final_b, cnts + 4, outF);

  // ---- tail ----
  k_tail<<<16, 256, 0, stream>>>(maskI, outF);
}